// Round 8
// baseline (166.247 us; speedup 1.0000x reference)
//
#include <hip/hip_runtime.h>
#include <hip/hip_bf16.h>
#include <stdint.h>

typedef unsigned short u16;
typedef __attribute__((ext_vector_type(4))) float f32x4;
typedef __attribute__((ext_vector_type(8))) short s16x8;
typedef __attribute__((ext_vector_type(4))) float fvec4;

#define NH 12
#define DH 64
#define HID 768
#define SEQ 197
#define SP 208            // padded seq rows for Q/K slabs
#define VP 224            // padded seq cols for Vt slab
#define NREL 732
#define BATCH 64
#define MROWS (BATCH*SEQ) // 12608
#define NCAT (3*HID)      // 2304
#define AWG (768*13)      // 9984 attn blocks = 8 * 1248

// qkv gemm geometry: 256x256 tile, BK=32, quad-buffered
#define QBK 32
#define QMT 50            // 50*256 = 12800 >= 12608
#define QNT 9             // 9*256 = 2304
#define QWG (QMT*QNT)     // 450
#define KTN 24            // 768/32

static __device__ __forceinline__ u16 f2bf(float f) {
  union { float f; uint32_t u; } v; v.f = f;
  uint32_t u = v.u;
  return (u16)((u + 0x7FFFu + ((u >> 16) & 1u)) >> 16);
}

// ---------------- prep: hidden fp32 -> bf16 ----------------
__global__ __launch_bounds__(256) void conv_x(const float* __restrict__ x, u16* __restrict__ xb, int n8) {
  int i = blockIdx.x * 256 + threadIdx.x;
  if (i >= n8) return;
  fvec4 a = ((const fvec4*)x)[2 * i];
  fvec4 b = ((const fvec4*)x)[2 * i + 1];
  s16x8 r;
  r[0] = (short)f2bf(a[0]); r[1] = (short)f2bf(a[1]); r[2] = (short)f2bf(a[2]); r[3] = (short)f2bf(a[3]);
  r[4] = (short)f2bf(b[0]); r[5] = (short)f2bf(b[1]); r[6] = (short)f2bf(b[2]); r[7] = (short)f2bf(b[3]);
  ((s16x8*)xb)[i] = r;
}

// ---------------- prep: W's -> transposed concat bf16 [NCAT][HID] ----------------
__global__ __launch_bounds__(256) void conv_w(const float* __restrict__ Wq, const float* __restrict__ Wk,
                                              const float* __restrict__ Wv, u16* __restrict__ Wt) {
  __shared__ float t[64][65];
  int n0 = blockIdx.x * 64;  // output row block (0..2303)
  int k0 = blockIdx.y * 64;  // k block (0..767)
  int m = n0 / HID;
  const float* W = (m == 0) ? Wq : ((m == 1) ? Wk : Wv);
  int nn0 = n0 - m * HID;
  for (int i = threadIdx.x; i < 64 * 64; i += 256) {
    int r = i >> 6, c = i & 63;
    t[r][c] = W[(size_t)(k0 + r) * HID + nn0 + c];   // coalesced read
  }
  __syncthreads();
  for (int i = threadIdx.x; i < 64 * 64; i += 256) {
    int r = i >> 6, c = i & 63;
    Wt[(size_t)(n0 + r) * HID + k0 + c] = f2bf(t[c][r]);  // coalesced write
  }
}

// ---------------- prep: bias concat (bq, 0, bv) ----------------
__global__ __launch_bounds__(256) void conv_b(const float* __restrict__ bq, const float* __restrict__ bv,
                                              float* __restrict__ bc) {
  int i = blockIdx.x * 256 + threadIdx.x;
  if (i < NCAT) {
    int m = i / HID, r = i - m * HID;
    bc[i] = (m == 0) ? bq[r] : ((m == 2) ? bv[r] : 0.f);
  }
}

// ---------------- prep: expand rel-pos bias to dense [NH][208][208] f32 ----------------
__global__ __launch_bounds__(256) void expand_bias(const float* __restrict__ bias_table, float* __restrict__ Bx) {
  int i = blockIdx.x * 256 + threadIdx.x;
  if (i >= NH * 208 * 208) return;
  int h = i / (208 * 208);
  int r = i - h * 208 * 208;
  int q = r / 208, k = r - q * 208;
  float v;
  if (k >= SEQ) v = -1e30f;       // mask padded k
  else if (q >= SEQ) v = 0.f;     // padded q rows: unused
  else {
    int idx;
    if (q == 0) idx = (k == 0) ? 731 : 729;
    else if (k == 0) idx = 730;
    else {
      int iq = (q - 1) / 14, jq = (q - 1) % 14;
      int ik = (k - 1) / 14, jk = (k - 1) % 14;
      idx = (iq - ik + 13) * 27 + (jq - jk + 13);
    }
    v = bias_table[(size_t)idx * NH + h];
  }
  Bx[i] = v;
}

// ---------------- fused QKV GEMM: [12608x768]x[768x2304], bf16 MFMA ----------------
// 256x256 tile, BK=32, 8 waves (2M x 4N), QUAD-buffered LDS (4 x (A 16K + B 16K)
// = 128 KiB, 1 block/CU). Per K-step: issue stage(t+3), ds_read frags(t),
// 32 MFMA, asm s_waitcnt vmcnt(8) (t+1 landed; t+2/t+3 stay IN FLIGHT across
// the raw s_barrier - no vmcnt(0) drain in the main loop). Every half-tile is
// staged by ALL 8 waves (2 chunks each) so per-wave vmcnt + barrier is a valid
// cross-wave landing guarantee. XOR swizzle slot^=(row>>2)&3, inverse on the
// global source (global_load_lds writes linearly), applied on ds_read.

static __device__ __forceinline__ void stage_qkv(const u16* __restrict__ Xb, const u16* __restrict__ Wt,
                                                 int arow0, int brow0, int k0,
                                                 u16* Ab, u16* Bb, int w, int l) {
  const int srow = l >> 2;                       // row within 16-row chunk
  const int scol = (l & 3) ^ ((l >> 4) & 3);     // inverse-swizzled 16B slot
#pragma unroll
  for (int i = 0; i < 2; ++i) {
    const int ch = 2 * w + i;                    // wave-uniform 0..15
    int ga = arow0 + ch * 16 + srow; if (ga > MROWS - 1) ga = MROWS - 1;
    __builtin_amdgcn_global_load_lds((const __attribute__((address_space(1))) void*)
                                         (Xb + (size_t)ga * HID + k0 + scol * 8),
                                     (__attribute__((address_space(3))) void*)(Ab + ch * 512),
                                     16, 0, 0);
    const int gb = brow0 + ch * 16 + srow;       // N = 2304 exact, no clamp
    __builtin_amdgcn_global_load_lds((const __attribute__((address_space(1))) void*)
                                         (Wt + (size_t)gb * HID + k0 + scol * 8),
                                     (__attribute__((address_space(3))) void*)(Bb + ch * 512),
                                     16, 0, 0);
  }
}

__global__ __launch_bounds__(512, 1) void qkv_gemm(const u16* __restrict__ Xb, const u16* __restrict__ Wt,
                                                   const float* __restrict__ bc, u16* __restrict__ Qw,
                                                   u16* __restrict__ Kw, u16* __restrict__ Vw) {
  __shared__ u16 Abuf[4][256 * QBK];   // 4 x 16 KiB
  __shared__ u16 Bbuf[4][256 * QBK];   // 4 x 16 KiB  (128 KiB total)
  const int tid = threadIdx.x;
  const int w = tid >> 6, l = tid & 63;
  const int wm = w >> 2, wn = w & 3;             // 2x4 wave grid; per-wave C = 128x64
  const int lg = l >> 4, li = l & 15;

  // bijective XCD chunking (m204): nwg=450, q=56, r=2
  const int lin = blockIdx.x;
  const int xcd = lin & 7;
  const int pos = lin >> 3;
  const int work = (xcd < 2 ? xcd * 57 : 114 + (xcd - 2) * 56) + pos;
  const int mt = work / QNT, nt = work - mt * QNT;
  const int arow0 = mt * 256, brow0 = nt * 256;

  f32x4 acc[8][4] = {};

  // prologue: stage tiles 0..2; wait tile 0 (leave 1,2 in flight)
  stage_qkv(Xb, Wt, arow0, brow0, 0 * QBK, Abuf[0], Bbuf[0], w, l);
  stage_qkv(Xb, Wt, arow0, brow0, 1 * QBK, Abuf[1], Bbuf[1], w, l);
  stage_qkv(Xb, Wt, arow0, brow0, 2 * QBK, Abuf[2], Bbuf[2], w, l);
  asm volatile("s_waitcnt vmcnt(8)" ::: "memory");
  __builtin_amdgcn_sched_barrier(0);
  __builtin_amdgcn_s_barrier();
  __builtin_amdgcn_sched_barrier(0);

  const int swb = ((lg ^ (li >> 2)) << 4);       // swizzled 16B slot (byte offset)
  const int abase = (wm * 128 + li) * 64 + swb;  // + mi*16*64
  const int bbase = (wn * 64 + li) * 64 + swb;   // + ni*16*64

#pragma unroll
  for (int t = 0; t < KTN; ++t) {
    if (t + 3 < KTN)
      stage_qkv(Xb, Wt, arow0, brow0, (t + 3) * QBK, Abuf[(t + 3) & 3], Bbuf[(t + 3) & 3], w, l);

    s16x8 af[8], bf[4];
    const char* Ab = (const char*)Abuf[t & 3];
    const char* Bb = (const char*)Bbuf[t & 3];
#pragma unroll
    for (int mi = 0; mi < 8; ++mi)
      af[mi] = *(const s16x8*)(Ab + abase + mi * 1024);
#pragma unroll
    for (int ni = 0; ni < 4; ++ni)
      bf[ni] = *(const s16x8*)(Bb + bbase + ni * 1024);

#pragma unroll
    for (int mi = 0; mi < 8; ++mi)
#pragma unroll
      for (int ni = 0; ni < 4; ++ni)
        acc[mi][ni] = __builtin_amdgcn_mfma_f32_16x16x32_bf16(af[mi], bf[ni], acc[mi][ni], 0, 0, 0);

    // counted wait: tile t+1 landed; newer tiles stay in flight across barrier
    if (t <= KTN - 4)      { asm volatile("s_waitcnt vmcnt(8)" ::: "memory"); }
    else if (t == KTN - 3) { asm volatile("s_waitcnt vmcnt(4)" ::: "memory"); }
    else                   { asm volatile("s_waitcnt vmcnt(0)" ::: "memory"); }
    __builtin_amdgcn_sched_barrier(0);
    __builtin_amdgcn_s_barrier();
    __builtin_amdgcn_sched_barrier(0);
  }

  // ---------------- uniform m-pure epilogue (block-uniform dst/scale/stride) ----------------
  const int mblk = nt / 3;                 // 0=Q, 1=K, 2=V  (256-col tiles never straddle)
  u16* __restrict__ dst = (mblk == 0) ? Qw : ((mblk == 1) ? Kw : Vw);
  const float scale = (mblk == 0) ? 0.125f : 1.0f;
  const int STR = (mblk == 2) ? SEQ : SP;  // rows per bh slab (V is tight: 197)
  int hv[4], dv[4]; float bcv[4];
#pragma unroll
  for (int ni = 0; ni < 4; ++ni) {
    int col = brow0 + wn * 64 + ni * 16 + li;
    int cloc = col - mblk * HID;
    hv[ni] = cloc >> 6; dv[ni] = cloc & 63;
    bcv[ni] = bc[col];
  }
#pragma unroll
  for (int mi = 0; mi < 8; ++mi) {
#pragma unroll
    for (int j = 0; j < 4; ++j) {
      int row = arow0 + wm * 128 + mi * 16 + lg * 4 + j;
      if (row < MROWS) {
        int b = row / SEQ, s = row - b * SEQ;
#pragma unroll
        for (int ni = 0; ni < 4; ++ni)
          dst[((size_t)(b * NH + hv[ni]) * STR + s) * DH + dv[ni]] = f2bf((acc[mi][ni][j] + bcv[ni]) * scale);
      }
    }
  }
}

// ---------------- transpose V: [bh][197][64] -> [bh][64][224] (tail zero) ----------------
__global__ __launch_bounds__(256) void transpose_v(const u16* __restrict__ Vw, u16* __restrict__ Vt) {
  __shared__ u16 T[64][209];       // [d][s] u16; odd stride spreads banks
  const int bh = blockIdx.x;
  const int tid = threadIdx.x;
  const u16* src = Vw + (size_t)bh * SEQ * DH;
  for (int i = tid; i < 208 * 64; i += 256) {
    int r = i >> 6, c = i & 63;    // consecutive tid -> consecutive c (coalesced)
    u16 v = (r < SEQ) ? src[(size_t)r * DH + c] : (u16)0;
    T[c][r] = v;
  }
  __syncthreads();
  uint32_t* __restrict__ dst = (uint32_t*)(Vt + (size_t)bh * DH * VP);
  for (int i = tid; i < 64 * 112; i += 256) {
    int d = i / 112, s2 = i - d * 112;   // consecutive tid -> consecutive s2 (coalesced)
    uint32_t v = 0;
    if (s2 < 104) v = (uint32_t)T[d][2 * s2] | ((uint32_t)T[d][2 * s2 + 1] << 16);
    dst[(size_t)d * 112 + s2] = v;
  }
}

// ---------------- fused attention: 1 WAVE per (bh, qf) — zero barriers ----------------
// XCD-chunked block swizzle: 9984 = 8*1248 exactly; the 13 blocks sharing one
// bh's K/V/Q slabs run consecutively on ONE XCD -> slabs + Bx stay L2-resident.
__global__ __launch_bounds__(64, 3) void attn(const u16* __restrict__ Qw, const u16* __restrict__ Kw,
                                              const u16* __restrict__ Vt, const float* __restrict__ Bx,
                                              float* __restrict__ out) {
  __shared__ u16 P[16 * 232];      // 16 q-rows x 208 k-cols (+pad), conflict-free b128
  const int l = threadIdx.x;
  const int lg = l >> 4, li = l & 15;
  const int lin = blockIdx.x;
  const int work = (lin & 7) * (AWG / 8) + (lin >> 3);   // bijective XCD chunking
  const int bh = work / 13, qf = work - bh * 13;
  const int b = bh / NH, h = bh - b * NH;

  // zero tail cols 208..231 (read by PV t-loop, never written)
  for (int t = l; t < 16 * 24; t += 64) {
    int rr = t / 24, cc = t - rr * 24;
    P[rr * 232 + 208 + cc] = 0;
  }

  const u16* Qb = Qw + (size_t)bh * SP * DH;
  const u16* Kb = Kw + (size_t)bh * SP * DH;
  const u16* Vb = Vt + (size_t)bh * DH * VP;
  const float* Bh = Bx + ((size_t)h * 208 + qf * 16 + lg * 4) * 208;

  // ---- QK^T ----
  s16x8 a0 = *(const s16x8*)(Qb + (size_t)(qf * 16 + li) * DH + lg * 8);
  s16x8 a1 = *(const s16x8*)(Qb + (size_t)(qf * 16 + li) * DH + 32 + lg * 8);
  f32x4 S[13];
#pragma unroll
  for (int kf = 0; kf < 13; ++kf) {
    s16x8 b0 = *(const s16x8*)(Kb + (size_t)(kf * 16 + li) * DH + lg * 8);
    s16x8 b1 = *(const s16x8*)(Kb + (size_t)(kf * 16 + li) * DH + 32 + lg * 8);
    f32x4 c = {};
    c = __builtin_amdgcn_mfma_f32_16x16x32_bf16(a0, b0, c, 0, 0, 0);
    c = __builtin_amdgcn_mfma_f32_16x16x32_bf16(a1, b1, c, 0, 0, 0);
    S[kf] = c;
  }

  // ---- + bias (mask baked in) ----
#pragma unroll
  for (int kf = 0; kf < 13; ++kf)
#pragma unroll
    for (int j = 0; j < 4; ++j)
      S[kf][j] += Bh[j * 208 + kf * 16 + li];

  // ---- softmax over 13 regs x 16 lanes (per 16-lane group) ----
  float rinv[4];
#pragma unroll
  for (int j = 0; j < 4; ++j) {
    float m = S[0][j];
#pragma unroll
    for (int kf = 1; kf < 13; ++kf) m = fmaxf(m, S[kf][j]);
    m = fmaxf(m, __shfl_xor(m, 1));
    m = fmaxf(m, __shfl_xor(m, 2));
    m = fmaxf(m, __shfl_xor(m, 4));
    m = fmaxf(m, __shfl_xor(m, 8));
    float sum = 0.f;
#pragma unroll
    for (int kf = 0; kf < 13; ++kf) {
      float p = __expf(S[kf][j] - m);
      S[kf][j] = p;
      sum += p;
    }
    sum += __shfl_xor(sum, 1);
    sum += __shfl_xor(sum, 2);
    sum += __shfl_xor(sum, 4);
    sum += __shfl_xor(sum, 8);
    rinv[j] = 1.0f / sum;
  }

  // ---- transpose P into LDS (bf16) ----
#pragma unroll
  for (int kf = 0; kf < 13; ++kf)
#pragma unroll
    for (int j = 0; j < 4; ++j)
      P[(lg * 4 + j) * 232 + kf * 16 + li] = f2bf(S[kf][j]);

  // ---- PV ----
#pragma unroll
  for (int nf = 0; nf < 4; ++nf) {
    f32x4 c = {};
#pragma unroll
    for (int t = 0; t < 7; ++t) {
      s16x8 pa = *(const s16x8*)(&P[li * 232 + t * 32 + lg * 8]);
      s16x8 vb = *(const s16x8*)(Vb + (size_t)(nf * 16 + li) * VP + t * 32 + lg * 8);
      c = __builtin_amdgcn_mfma_f32_16x16x32_bf16(pa, vb, c, 0, 0, 0);
    }
#pragma unroll
    for (int j = 0; j < 4; ++j) {
      int q = qf * 16 + lg * 4 + j;
      if (q < SEQ)
        out[((size_t)(b * SEQ + q)) * HID + h * DH + nf * 16 + li] = c[j] * rinv[j];
    }
  }
}

extern "C" void kernel_launch(void* const* d_in, const int* in_sizes, int n_in,
                              void* d_out, int out_size, void* d_ws, size_t ws_size,
                              hipStream_t stream) {
  const float* hidden = (const float*)d_in[0];
  const float* Wq = (const float*)d_in[1];
  const float* bq = (const float*)d_in[2];
  const float* Wk = (const float*)d_in[3];
  const float* Wv = (const float*)d_in[4];
  const float* bv = (const float*)d_in[5];
  const float* btab = (const float*)d_in[6];
  float* out = (float*)d_out;

  // workspace layout (peak 85,260,288 B; Vt overlays dead Xb/Wt after qkv):
  char* ws = (char*)d_ws;
  u16* Xb  = (u16*)(ws);                       // [0, 19,365,888)   12608*768*2
  u16* Wt  = (u16*)(ws + 19365888);            // [.., 22,904,832)  2304*768*2
  float* bc = (float*)(ws + 22904832);         // [.., 22,914,048)  2304*4
  float* Bx = (float*)(ws + 22914048);         // [.., 24,990,720)  12*208*208*4
  u16* Qw  = (u16*)(ws + 24990720);            // [.., 45,437,952)  768*208*64*2
  u16* Kw  = (u16*)(ws + 45437952);            // [.., 65,885,184)  768*208*64*2
  u16* Vw  = (u16*)(ws + 65885184);            // [.., 85,260,288)  768*197*64*2
  u16* Vt  = (u16*)(ws);                       // overlays Xb/Wt: 768*64*224*2 = 22,020,096

  conv_x<<<dim3(4728), dim3(256), 0, stream>>>(hidden, Xb, (MROWS * HID) / 8);
  conv_w<<<dim3(NCAT / 64, HID / 64), dim3(256), 0, stream>>>(Wq, Wk, Wv, Wt);
  conv_b<<<dim3(9), dim3(256), 0, stream>>>(bq, bv, bc);
  qkv_gemm<<<dim3(QWG), dim3(512), 0, stream>>>(Xb, Wt, bc, Qw, Kw, Vw);
  transpose_v<<<dim3(768), dim3(256), 0, stream>>>(Vw, Vt);
  expand_bias<<<dim3((NH * 208 * 208 + 255) / 256), dim3(256), 0, stream>>>(btab, Bx);
  attn<<<dim3(AWG), dim3(64), 0, stream>>>(Qw, Kw, Vt, Bx, out);
}

// Round 9
// 166.172 us; speedup vs baseline: 1.0005x; 1.0005x over previous
//
#include <hip/hip_runtime.h>
#include <hip/hip_bf16.h>
#include <stdint.h>

typedef unsigned short u16;
typedef __attribute__((ext_vector_type(4))) float f32x4;
typedef __attribute__((ext_vector_type(8))) short s16x8;
typedef __attribute__((ext_vector_type(4))) float fvec4;

#define NH 12
#define DH 64
#define HID 768
#define SEQ 197
#define SP 208            // padded seq rows for Q/K slabs
#define VP 224            // padded seq cols for Vt slab
#define NREL 732
#define BATCH 64
#define MROWS (BATCH*SEQ) // 12608
#define NCAT (3*HID)      // 2304
#define BK 64
#define MT 99             // grid tiles in M (99*128 = 12672 >= 12608)
#define NT 18             // grid tiles in N (18*128 = 2304)
#define NWG (MT*NT)       // 1782
#define AUNITS (768*13)   // 9984 attn work units
#define AWG (AUNITS/2)    // 4992 two-wave blocks = 8 * 624

static __device__ __forceinline__ u16 f2bf(float f) {
  union { float f; uint32_t u; } v; v.f = f;
  uint32_t u = v.u;
  return (u16)((u + 0x7FFFu + ((u >> 16) & 1u)) >> 16);
}

// ---------------- prep: hidden fp32 -> bf16 ----------------
__global__ __launch_bounds__(256) void conv_x(const float* __restrict__ x, u16* __restrict__ xb, int n8) {
  int i = blockIdx.x * 256 + threadIdx.x;
  if (i >= n8) return;
  fvec4 a = ((const fvec4*)x)[2 * i];
  fvec4 b = ((const fvec4*)x)[2 * i + 1];
  s16x8 r;
  r[0] = (short)f2bf(a[0]); r[1] = (short)f2bf(a[1]); r[2] = (short)f2bf(a[2]); r[3] = (short)f2bf(a[3]);
  r[4] = (short)f2bf(b[0]); r[5] = (short)f2bf(b[1]); r[6] = (short)f2bf(b[2]); r[7] = (short)f2bf(b[3]);
  ((s16x8*)xb)[i] = r;
}

// ---------------- prep: W's -> transposed concat bf16 [NCAT][HID] ----------------
__global__ __launch_bounds__(256) void conv_w(const float* __restrict__ Wq, const float* __restrict__ Wk,
                                              const float* __restrict__ Wv, u16* __restrict__ Wt) {
  __shared__ float t[64][65];
  int n0 = blockIdx.x * 64;  // output row block (0..2303)
  int k0 = blockIdx.y * 64;  // k block (0..767)
  int m = n0 / HID;
  const float* W = (m == 0) ? Wq : ((m == 1) ? Wk : Wv);
  int nn0 = n0 - m * HID;
  for (int i = threadIdx.x; i < 64 * 64; i += 256) {
    int r = i >> 6, c = i & 63;
    t[r][c] = W[(size_t)(k0 + r) * HID + nn0 + c];   // coalesced read
  }
  __syncthreads();
  for (int i = threadIdx.x; i < 64 * 64; i += 256) {
    int r = i >> 6, c = i & 63;
    Wt[(size_t)(n0 + r) * HID + k0 + c] = f2bf(t[c][r]);  // coalesced write
  }
}

// ---------------- prep: bias concat (bq, 0, bv) ----------------
__global__ __launch_bounds__(256) void conv_b(const float* __restrict__ bq, const float* __restrict__ bv,
                                              float* __restrict__ bc) {
  int i = blockIdx.x * 256 + threadIdx.x;
  if (i < NCAT) {
    int m = i / HID, r = i - m * HID;
    bc[i] = (m == 0) ? bq[r] : ((m == 2) ? bv[r] : 0.f);
  }
}

// ---------------- prep: expand rel-pos bias to dense [NH][208][208] f32 ----------------
__global__ __launch_bounds__(256) void expand_bias(const float* __restrict__ bias_table, float* __restrict__ Bx) {
  int i = blockIdx.x * 256 + threadIdx.x;
  if (i >= NH * 208 * 208) return;
  int h = i / (208 * 208);
  int r = i - h * 208 * 208;
  int q = r / 208, k = r - q * 208;
  float v;
  if (k >= SEQ) v = -1e30f;       // mask padded k
  else if (q >= SEQ) v = 0.f;     // padded q rows: unused
  else {
    int idx;
    if (q == 0) idx = (k == 0) ? 731 : 729;
    else if (k == 0) idx = 730;
    else {
      int iq = (q - 1) / 14, jq = (q - 1) % 14;
      int ik = (k - 1) / 14, jk = (k - 1) % 14;
      idx = (iq - ik + 13) * 27 + (jq - jk + 13);
    }
    v = bias_table[(size_t)idx * NH + h];
  }
  Bx[i] = v;
}

// ---------------- fused QKV GEMM (round-7 proven: 77 us, MfmaUtil 23%, 0 conflicts) ----------------
// 128x128 tile, BK=64, 4 waves (2x2), double-buffered (4 distinct 16 KiB LDS
// arrays = 64 KiB total -> 2 blocks/CU). Per K-step: stage(t+1 -> other buf),
// compute(t), ONE __syncthreads. XOR-swizzled LDS via inverse-swizzled source.

static __device__ __forceinline__ void stage128(const u16* __restrict__ gbase, int grow0, int growmax,
                                                u16* lds, int w, int l) {
#pragma unroll
  for (int i = 0; i < 4; ++i) {
    int ch = w * 4 + i;                    // wave-uniform 0..15
    int r = ch * 8 + (l >> 3);
    int grow = grow0 + r; if (grow > growmax) grow = growmax;
    int c = (l & 7) ^ (l >> 3);            // inverse swizzle on source
    const u16* g = gbase + (size_t)grow * HID + c * 8;
    __builtin_amdgcn_global_load_lds((const __attribute__((address_space(1))) void*)g,
                                     (__attribute__((address_space(3))) void*)(lds + ch * 512),
                                     16, 0, 0);
  }
}

static __device__ __forceinline__ void compute128(const u16* As, const u16* Bs, int wr, int wc,
                                                  int li, int lg, f32x4 acc[4][4]) {
#pragma unroll
  for (int kk = 0; kk < 2; ++kk) {
    s16x8 af[4], bf[4];
#pragma unroll
    for (int mi = 0; mi < 4; ++mi) {
      int r = wr * 64 + mi * 16 + li;
      int c = (kk * 4 + lg) ^ (r & 7);
      af[mi] = *(const s16x8*)((const char*)As + r * 128 + c * 16);
    }
#pragma unroll
    for (int ni = 0; ni < 4; ++ni) {
      int r = wc * 64 + ni * 16 + li;
      int c = (kk * 4 + lg) ^ (r & 7);
      bf[ni] = *(const s16x8*)((const char*)Bs + r * 128 + c * 16);
    }
#pragma unroll
    for (int mi = 0; mi < 4; ++mi)
#pragma unroll
      for (int ni = 0; ni < 4; ++ni)
        acc[mi][ni] = __builtin_amdgcn_mfma_f32_16x16x32_bf16(af[mi], bf[ni], acc[mi][ni], 0, 0, 0);
  }
}

__global__ __launch_bounds__(256, 2) void qkv_gemm(const u16* __restrict__ Xb, const u16* __restrict__ Wt,
                                                   const float* __restrict__ bc, u16* __restrict__ Qw,
                                                   u16* __restrict__ Kw, u16* __restrict__ Vw) {
  __shared__ u16 As0[128 * BK];
  __shared__ u16 Bs0[128 * BK];
  __shared__ u16 As1[128 * BK];
  __shared__ u16 Bs1[128 * BK];
  const int tid = threadIdx.x;
  const int w = tid >> 6, l = tid & 63;
  const int wr = w >> 1, wc = w & 1;        // 2x2 wave grid, 64x64 per wave
  const int lg = l >> 4, li = l & 15;

  // bijective XCD chunking (m204): nwg=1782, q=222, r=6
  const int lin = blockIdx.x;
  const int xcd = lin & 7;
  const int pos = lin >> 3;
  const int work = (xcd < 6 ? xcd * 223 : 6 * 223 + (xcd - 6) * 222) + pos;
  const int mt = work / NT, nt = work - mt * NT;
  const int arow0 = mt * 128, brow0 = nt * 128;

  f32x4 acc[4][4] = {};

  stage128(Xb, arow0, MROWS - 1, As0, w, l);
  stage128(Wt, brow0, NCAT - 1, Bs0, w, l);
  __syncthreads();

  for (int kt2 = 0; kt2 < 6; ++kt2) {
    const int kt = kt2 * 2;
    // even: prefetch kt+1 -> buf1; compute kt from buf0; sync frees buf0
    stage128(Xb + (kt + 1) * BK, arow0, MROWS - 1, As1, w, l);
    stage128(Wt + (kt + 1) * BK, brow0, NCAT - 1, Bs1, w, l);
    compute128(As0, Bs0, wr, wc, li, lg, acc);
    __syncthreads();
    // odd: prefetch kt+2 -> buf0; compute kt+1 from buf1; sync frees buf1
    if (kt2 < 5) {
      stage128(Xb + (kt + 2) * BK, arow0, MROWS - 1, As0, w, l);
      stage128(Wt + (kt + 2) * BK, brow0, NCAT - 1, Bs0, w, l);
    }
    compute128(As1, Bs1, wr, wc, li, lg, acc);
    __syncthreads();
  }

  // ---------------- uniform m-pure epilogue (block-uniform dst/scale/stride) ----------------
  const int mblk = nt / 6;                 // 0=Q, 1=K, 2=V
  u16* __restrict__ dst = (mblk == 0) ? Qw : ((mblk == 1) ? Kw : Vw);
  const float scale = (mblk == 0) ? 0.125f : 1.0f;
  const int STR = (mblk == 2) ? SEQ : SP;  // rows per bh slab (V is tight: 197)
  int hv[4], dv[4]; float bcv[4];
#pragma unroll
  for (int ni = 0; ni < 4; ++ni) {
    int col = brow0 + wc * 64 + ni * 16 + li;
    int cloc = col - mblk * HID;
    hv[ni] = cloc >> 6; dv[ni] = cloc & 63;
    bcv[ni] = bc[col];
  }
#pragma unroll
  for (int mi = 0; mi < 4; ++mi) {
#pragma unroll
    for (int j = 0; j < 4; ++j) {
      int row = arow0 + wr * 64 + mi * 16 + lg * 4 + j;
      if (row < MROWS) {
        int b = row / SEQ, s = row - b * SEQ;
#pragma unroll
        for (int ni = 0; ni < 4; ++ni)
          dst[((size_t)(b * NH + hv[ni]) * STR + s) * DH + dv[ni]] = f2bf((acc[mi][ni][j] + bcv[ni]) * scale);
      }
    }
  }
}

// ---------------- transpose V: [bh][197][64] -> [bh][64][224] (tail zero) ----------------
__global__ __launch_bounds__(256) void transpose_v(const u16* __restrict__ Vw, u16* __restrict__ Vt) {
  __shared__ u16 T[64][209];       // [d][s] u16; odd stride spreads banks
  const int bh = blockIdx.x;
  const int tid = threadIdx.x;
  const u16* src = Vw + (size_t)bh * SEQ * DH;
  for (int i = tid; i < 208 * 64; i += 256) {
    int r = i >> 6, c = i & 63;    // consecutive tid -> consecutive c (coalesced)
    u16 v = (r < SEQ) ? src[(size_t)r * DH + c] : (u16)0;
    T[c][r] = v;
  }
  __syncthreads();
  uint32_t* __restrict__ dst = (uint32_t*)(Vt + (size_t)bh * DH * VP);
  for (int i = tid; i < 64 * 112; i += 256) {
    int d = i / 112, s2 = i - d * 112;   // consecutive tid -> consecutive s2 (coalesced)
    uint32_t v = 0;
    if (s2 < 104) v = (uint32_t)T[d][2 * s2] | ((uint32_t)T[d][2 * s2 + 1] << 16);
    dst[(size_t)d * 112 + s2] = v;
  }
}

// ---------------- fused attention: 2 independent WAVES per block, zero barriers ----------------
// Round-6 profile: Occupancy 50% = the 16-workgroup/CU cap with 64-thread blocks.
// 128-thread blocks (2 waves, private P sections, no syncthreads) lift the cap:
// LDS 14.8 KB/block -> 11 blocks/CU -> 22 waves/CU (~69%). XCD-chunked swizzle
// keeps each bh's 13 units on one XCD (K/V/Q/Bx L2-resident).
__global__ __launch_bounds__(128) void attn(const u16* __restrict__ Qw, const u16* __restrict__ Kw,
                                            const u16* __restrict__ Vt, const float* __restrict__ Bx,
                                            float* __restrict__ out) {
  __shared__ u16 P[2][16 * 232];   // per-wave P transpose buffer, conflict-free b128
  const int tid = threadIdx.x;
  const int w = tid >> 6, l = tid & 63;
  const int lg = l >> 4, li = l & 15;
  const int lin = blockIdx.x;
  const int work = (lin & 7) * (AWG / 8) + (lin >> 3);   // bijective XCD chunking
  const int unit = work * 2 + w;                          // 0..9983
  const int bh = unit / 13, qf = unit - bh * 13;
  const int b = bh / NH, h = bh - b * NH;

  // zero tail cols 208..231 of this wave's P (read by PV t-loop, never written)
  for (int t = l; t < 16 * 24; t += 64) {
    int rr = t / 24, cc = t - rr * 24;
    P[w][rr * 232 + 208 + cc] = 0;
  }

  const u16* Qb = Qw + (size_t)bh * SP * DH;
  const u16* Kb = Kw + (size_t)bh * SP * DH;
  const u16* Vb = Vt + (size_t)bh * DH * VP;
  const float* Bh = Bx + ((size_t)h * 208 + qf * 16 + lg * 4) * 208;

  // ---- QK^T ----
  s16x8 a0 = *(const s16x8*)(Qb + (size_t)(qf * 16 + li) * DH + lg * 8);
  s16x8 a1 = *(const s16x8*)(Qb + (size_t)(qf * 16 + li) * DH + 32 + lg * 8);
  f32x4 S[13];
#pragma unroll
  for (int kf = 0; kf < 13; ++kf) {
    s16x8 b0 = *(const s16x8*)(Kb + (size_t)(kf * 16 + li) * DH + lg * 8);
    s16x8 b1 = *(const s16x8*)(Kb + (size_t)(kf * 16 + li) * DH + 32 + lg * 8);
    f32x4 c = {};
    c = __builtin_amdgcn_mfma_f32_16x16x32_bf16(a0, b0, c, 0, 0, 0);
    c = __builtin_amdgcn_mfma_f32_16x16x32_bf16(a1, b1, c, 0, 0, 0);
    S[kf] = c;
  }

  // ---- + bias (mask baked in) ----
#pragma unroll
  for (int kf = 0; kf < 13; ++kf)
#pragma unroll
    for (int j = 0; j < 4; ++j)
      S[kf][j] += Bh[j * 208 + kf * 16 + li];

  // ---- softmax over 13 regs x 16 lanes (per 16-lane group) ----
  float rinv[4];
#pragma unroll
  for (int j = 0; j < 4; ++j) {
    float m = S[0][j];
#pragma unroll
    for (int kf = 1; kf < 13; ++kf) m = fmaxf(m, S[kf][j]);
    m = fmaxf(m, __shfl_xor(m, 1));
    m = fmaxf(m, __shfl_xor(m, 2));
    m = fmaxf(m, __shfl_xor(m, 4));
    m = fmaxf(m, __shfl_xor(m, 8));
    float sum = 0.f;
#pragma unroll
    for (int kf = 0; kf < 13; ++kf) {
      float p = __expf(S[kf][j] - m);
      S[kf][j] = p;
      sum += p;
    }
    sum += __shfl_xor(sum, 1);
    sum += __shfl_xor(sum, 2);
    sum += __shfl_xor(sum, 4);
    sum += __shfl_xor(sum, 8);
    rinv[j] = 1.0f / sum;
  }

  // ---- transpose P into LDS (bf16) ----
#pragma unroll
  for (int kf = 0; kf < 13; ++kf)
#pragma unroll
    for (int j = 0; j < 4; ++j)
      P[w][(lg * 4 + j) * 232 + kf * 16 + li] = f2bf(S[kf][j]);

  // ---- PV ----
#pragma unroll
  for (int nf = 0; nf < 4; ++nf) {
    f32x4 c = {};
#pragma unroll
    for (int t = 0; t < 7; ++t) {
      s16x8 pa = *(const s16x8*)(&P[w][li * 232 + t * 32 + lg * 8]);
      s16x8 vb = *(const s16x8*)(Vb + (size_t)(nf * 16 + li) * VP + t * 32 + lg * 8);
      c = __builtin_amdgcn_mfma_f32_16x16x32_bf16(pa, vb, c, 0, 0, 0);
    }
#pragma unroll
    for (int j = 0; j < 4; ++j) {
      int q = qf * 16 + lg * 4 + j;
      if (q < SEQ)
        out[((size_t)(b * SEQ + q)) * HID + h * DH + nf * 16 + li] = c[j] * rinv[j];
    }
  }
}

extern "C" void kernel_launch(void* const* d_in, const int* in_sizes, int n_in,
                              void* d_out, int out_size, void* d_ws, size_t ws_size,
                              hipStream_t stream) {
  const float* hidden = (const float*)d_in[0];
  const float* Wq = (const float*)d_in[1];
  const float* bq = (const float*)d_in[2];
  const float* Wk = (const float*)d_in[3];
  const float* Wv = (const float*)d_in[4];
  const float* bv = (const float*)d_in[5];
  const float* btab = (const float*)d_in[6];
  float* out = (float*)d_out;

  // workspace layout (peak 85,260,288 B; Vt overlays dead Xb/Wt after qkv):
  char* ws = (char*)d_ws;
  u16* Xb  = (u16*)(ws);                       // [0, 19,365,888)   12608*768*2
  u16* Wt  = (u16*)(ws + 19365888);            // [.., 22,904,832)  2304*768*2
  float* bc = (float*)(ws + 22904832);         // [.., 22,914,048)  2304*4
  float* Bx = (float*)(ws + 22914048);         // [.., 24,990,720)  12*208*208*4
  u16* Qw  = (u16*)(ws + 24990720);            // [.., 45,437,952)  768*208*64*2
  u16* Kw  = (u16*)(ws + 45437952);            // [.., 65,885,184)  768*208*64*2
  u16* Vw  = (u16*)(ws + 65885184);            // [.., 85,260,288)  768*197*64*2
  u16* Vt  = (u16*)(ws);                       // overlays Xb/Wt: 768*64*224*2 = 22,020,096

  conv_x<<<dim3(4728), dim3(256), 0, stream>>>(hidden, Xb, (MROWS * HID) / 8);
  conv_w<<<dim3(NCAT / 64, HID / 64), dim3(256), 0, stream>>>(Wq, Wk, Wv, Wt);
  conv_b<<<dim3(9), dim3(256), 0, stream>>>(bq, bv, bc);
  qkv_gemm<<<dim3(NWG), dim3(256), 0, stream>>>(Xb, Wt, bc, Qw, Kw, Vw);
  transpose_v<<<dim3(768), dim3(256), 0, stream>>>(Vw, Vt);
  expand_bias<<<dim3((NH * 208 * 208 + 255) / 256), dim3(256), 0, stream>>>(btab, Bx);
  attn<<<dim3(AWG), dim3(128), 0, stream>>>(Qw, Kw, Vt, Bx, out);
}

// Round 10
// 162.926 us; speedup vs baseline: 1.0204x; 1.0199x over previous
//
#include <hip/hip_runtime.h>
#include <hip/hip_bf16.h>
#include <stdint.h>

typedef unsigned short u16;
typedef __attribute__((ext_vector_type(4))) float f32x4;
typedef __attribute__((ext_vector_type(8))) short s16x8;
typedef __attribute__((ext_vector_type(4))) unsigned short u16x4;
typedef __attribute__((ext_vector_type(4))) float fvec4;

#define NH 12
#define DH 64
#define HID 768
#define SEQ 197
#define SP 208            // padded seq rows for Q/K slabs
#define VP 224            // padded seq cols for Vt slab
#define NREL 732
#define BATCH 64
#define MROWS (BATCH*SEQ) // 12608
#define NCAT (3*HID)      // 2304
#define BK 64
#define MT 99             // grid tiles in M (99*128 = 12672 >= 12608)
#define NT 18             // grid tiles in N (18*128 = 2304)
#define NWG (MT*NT)       // 1782
#define AWG (768*13)      // 9984 attn blocks = 8 * 1248

static __device__ __forceinline__ u16 f2bf(float f) {
  union { float f; uint32_t u; } v; v.f = f;
  uint32_t u = v.u;
  return (u16)((u + 0x7FFFu + ((u >> 16) & 1u)) >> 16);
}
static __device__ __forceinline__ float bf2f(u16 v) {
  union { uint32_t u; float f; } x; x.u = ((uint32_t)v) << 16; return x.f;
}

// ---------------- prep: hidden fp32 -> bf16 ----------------
__global__ __launch_bounds__(256) void conv_x(const float* __restrict__ x, u16* __restrict__ xb, int n8) {
  int i = blockIdx.x * 256 + threadIdx.x;
  if (i >= n8) return;
  fvec4 a = ((const fvec4*)x)[2 * i];
  fvec4 b = ((const fvec4*)x)[2 * i + 1];
  s16x8 r;
  r[0] = (short)f2bf(a[0]); r[1] = (short)f2bf(a[1]); r[2] = (short)f2bf(a[2]); r[3] = (short)f2bf(a[3]);
  r[4] = (short)f2bf(b[0]); r[5] = (short)f2bf(b[1]); r[6] = (short)f2bf(b[2]); r[7] = (short)f2bf(b[3]);
  ((s16x8*)xb)[i] = r;
}

// ---------------- prep: W's -> transposed concat bf16 [NCAT][HID] ----------------
__global__ __launch_bounds__(256) void conv_w(const float* __restrict__ Wq, const float* __restrict__ Wk,
                                              const float* __restrict__ Wv, u16* __restrict__ Wt) {
  __shared__ float t[64][65];
  int n0 = blockIdx.x * 64;  // output row block (0..2303)
  int k0 = blockIdx.y * 64;  // k block (0..767)
  int m = n0 / HID;
  const float* W = (m == 0) ? Wq : ((m == 1) ? Wk : Wv);
  int nn0 = n0 - m * HID;
  for (int i = threadIdx.x; i < 64 * 64; i += 256) {
    int r = i >> 6, c = i & 63;
    t[r][c] = W[(size_t)(k0 + r) * HID + nn0 + c];   // coalesced read
  }
  __syncthreads();
  for (int i = threadIdx.x; i < 64 * 64; i += 256) {
    int r = i >> 6, c = i & 63;
    Wt[(size_t)(n0 + r) * HID + k0 + c] = f2bf(t[c][r]);  // coalesced write
  }
}

// ---------------- prep: bias concat (bq, 0, bv) ----------------
__global__ __launch_bounds__(256) void conv_b(const float* __restrict__ bq, const float* __restrict__ bv,
                                              float* __restrict__ bc) {
  int i = blockIdx.x * 256 + threadIdx.x;
  if (i < NCAT) {
    int m = i / HID, r = i - m * HID;
    bc[i] = (m == 0) ? bq[r] : ((m == 2) ? bv[r] : 0.f);
  }
}

// ---------------- prep: expand rel-pos bias, bf16, TRANSPOSED [NH][k=208][q=208] ----------------
// One ushort4 load in attn covers j=0..3 (q contiguous). Masked k>=197 rows = -1e30.
__global__ __launch_bounds__(256) void expand_bias(const float* __restrict__ bias_table, u16* __restrict__ Bxt) {
  int i = blockIdx.x * 256 + threadIdx.x;
  if (i >= NH * 208 * 208) return;
  int h = i / (208 * 208);
  int r = i - h * 208 * 208;
  int k = r / 208, q = r - k * 208;
  float v;
  if (k >= SEQ) v = -1e30f;       // mask padded k
  else if (q >= SEQ) v = 0.f;     // padded q rows: unused
  else {
    int idx;
    if (q == 0) idx = (k == 0) ? 731 : 729;
    else if (k == 0) idx = 730;
    else {
      int iq = (q - 1) / 14, jq = (q - 1) % 14;
      int ik = (k - 1) / 14, jk = (k - 1) % 14;
      idx = (iq - ik + 13) * 27 + (jq - jk + 13);
    }
    v = bias_table[(size_t)idx * NH + h];
  }
  Bxt[i] = f2bf(v);
}

// ---------------- fused QKV GEMM (round-7 proven: 77 us, MfmaUtil 23%, 0 conflicts) ----------------
// 128x128 tile, BK=64, 4 waves (2x2), double-buffered (4 distinct 16 KiB LDS
// arrays = 64 KiB total -> 2 blocks/CU). Per K-step: stage(t+1 -> other buf),
// compute(t), ONE __syncthreads. XOR-swizzled LDS via inverse-swizzled source.

static __device__ __forceinline__ void stage128(const u16* __restrict__ gbase, int grow0, int growmax,
                                                u16* lds, int w, int l) {
#pragma unroll
  for (int i = 0; i < 4; ++i) {
    int ch = w * 4 + i;                    // wave-uniform 0..15
    int r = ch * 8 + (l >> 3);
    int grow = grow0 + r; if (grow > growmax) grow = growmax;
    int c = (l & 7) ^ (l >> 3);            // inverse swizzle on source
    const u16* g = gbase + (size_t)grow * HID + c * 8;
    __builtin_amdgcn_global_load_lds((const __attribute__((address_space(1))) void*)g,
                                     (__attribute__((address_space(3))) void*)(lds + ch * 512),
                                     16, 0, 0);
  }
}

static __device__ __forceinline__ void compute128(const u16* As, const u16* Bs, int wr, int wc,
                                                  int li, int lg, f32x4 acc[4][4]) {
#pragma unroll
  for (int kk = 0; kk < 2; ++kk) {
    s16x8 af[4], bf[4];
#pragma unroll
    for (int mi = 0; mi < 4; ++mi) {
      int r = wr * 64 + mi * 16 + li;
      int c = (kk * 4 + lg) ^ (r & 7);
      af[mi] = *(const s16x8*)((const char*)As + r * 128 + c * 16);
    }
#pragma unroll
    for (int ni = 0; ni < 4; ++ni) {
      int r = wc * 64 + ni * 16 + li;
      int c = (kk * 4 + lg) ^ (r & 7);
      bf[ni] = *(const s16x8*)((const char*)Bs + r * 128 + c * 16);
    }
#pragma unroll
    for (int mi = 0; mi < 4; ++mi)
#pragma unroll
      for (int ni = 0; ni < 4; ++ni)
        acc[mi][ni] = __builtin_amdgcn_mfma_f32_16x16x32_bf16(af[mi], bf[ni], acc[mi][ni], 0, 0, 0);
  }
}

__global__ __launch_bounds__(256, 2) void qkv_gemm(const u16* __restrict__ Xb, const u16* __restrict__ Wt,
                                                   const float* __restrict__ bc, u16* __restrict__ Qw,
                                                   u16* __restrict__ Kw, u16* __restrict__ Vw) {
  __shared__ u16 As0[128 * BK];
  __shared__ u16 Bs0[128 * BK];
  __shared__ u16 As1[128 * BK];
  __shared__ u16 Bs1[128 * BK];
  const int tid = threadIdx.x;
  const int w = tid >> 6, l = tid & 63;
  const int wr = w >> 1, wc = w & 1;        // 2x2 wave grid, 64x64 per wave
  const int lg = l >> 4, li = l & 15;

  // bijective XCD chunking (m204): nwg=1782, q=222, r=6
  const int lin = blockIdx.x;
  const int xcd = lin & 7;
  const int pos = lin >> 3;
  const int work = (xcd < 6 ? xcd * 223 : 6 * 223 + (xcd - 6) * 222) + pos;
  const int mt = work / NT, nt = work - mt * NT;
  const int arow0 = mt * 128, brow0 = nt * 128;

  f32x4 acc[4][4] = {};

  stage128(Xb, arow0, MROWS - 1, As0, w, l);
  stage128(Wt, brow0, NCAT - 1, Bs0, w, l);
  __syncthreads();

  for (int kt2 = 0; kt2 < 6; ++kt2) {
    const int kt = kt2 * 2;
    // even: prefetch kt+1 -> buf1; compute kt from buf0; sync frees buf0
    stage128(Xb + (kt + 1) * BK, arow0, MROWS - 1, As1, w, l);
    stage128(Wt + (kt + 1) * BK, brow0, NCAT - 1, Bs1, w, l);
    compute128(As0, Bs0, wr, wc, li, lg, acc);
    __syncthreads();
    // odd: prefetch kt+2 -> buf0; compute kt+1 from buf1; sync frees buf1
    if (kt2 < 5) {
      stage128(Xb + (kt + 2) * BK, arow0, MROWS - 1, As0, w, l);
      stage128(Wt + (kt + 2) * BK, brow0, NCAT - 1, Bs0, w, l);
    }
    compute128(As1, Bs1, wr, wc, li, lg, acc);
    __syncthreads();
  }

  // ---------------- uniform m-pure epilogue (block-uniform dst/scale/stride) ----------------
  const int mblk = nt / 6;                 // 0=Q, 1=K, 2=V
  u16* __restrict__ dst = (mblk == 0) ? Qw : ((mblk == 1) ? Kw : Vw);
  const float scale = (mblk == 0) ? 0.125f : 1.0f;
  const int STR = (mblk == 2) ? SEQ : SP;  // rows per bh slab (V is tight: 197)
  int hv[4], dv[4]; float bcv[4];
#pragma unroll
  for (int ni = 0; ni < 4; ++ni) {
    int col = brow0 + wc * 64 + ni * 16 + li;
    int cloc = col - mblk * HID;
    hv[ni] = cloc >> 6; dv[ni] = cloc & 63;
    bcv[ni] = bc[col];
  }
#pragma unroll
  for (int mi = 0; mi < 4; ++mi) {
#pragma unroll
    for (int j = 0; j < 4; ++j) {
      int row = arow0 + wr * 64 + mi * 16 + lg * 4 + j;
      if (row < MROWS) {
        int b = row / SEQ, s = row - b * SEQ;
#pragma unroll
        for (int ni = 0; ni < 4; ++ni)
          dst[((size_t)(b * NH + hv[ni]) * STR + s) * DH + dv[ni]] = f2bf((acc[mi][ni][j] + bcv[ni]) * scale);
      }
    }
  }
}

// ---------------- transpose V: [bh][197][64] -> [bh][64][224] (tail zero) ----------------
__global__ __launch_bounds__(256) void transpose_v(const u16* __restrict__ Vw, u16* __restrict__ Vt) {
  __shared__ u16 T[64][209];       // [d][s] u16; odd stride spreads banks
  const int bh = blockIdx.x;
  const int tid = threadIdx.x;
  const u16* src = Vw + (size_t)bh * SEQ * DH;
  for (int i = tid; i < 208 * 64; i += 256) {
    int r = i >> 6, c = i & 63;    // consecutive tid -> consecutive c (coalesced)
    u16 v = (r < SEQ) ? src[(size_t)r * DH + c] : (u16)0;
    T[c][r] = v;
  }
  __syncthreads();
  uint32_t* __restrict__ dst = (uint32_t*)(Vt + (size_t)bh * DH * VP);
  for (int i = tid; i < 64 * 112; i += 256) {
    int d = i / 112, s2 = i - d * 112;   // consecutive tid -> consecutive s2 (coalesced)
    uint32_t v = 0;
    if (s2 < 104) v = (uint32_t)T[d][2 * s2] | ((uint32_t)T[d][2 * s2 + 1] << 16);
    dst[(size_t)d * 112 + s2] = v;
  }
}

// ---------------- fused attention: 1 WAVE per (bh, qf), ILP-pipelined ----------------
// r9 post-mortem: occupancy was NOT the limiter; VGPR=44 starved memory-level
// parallelism. (64,3) lifts the VGPR cap to ~168 (12 waves/CU): explicit 3-deep
// K-frag pipeline + batched bf16x4 bias loads + 4-deep V-frag pipeline keep
// ~6-10 loads in flight per wave. XCD chunking keeps each bh's units on one XCD.
__global__ __launch_bounds__(64, 3) void attn(const u16* __restrict__ Qw, const u16* __restrict__ Kw,
                                              const u16* __restrict__ Vt, const u16* __restrict__ Bxt,
                                              float* __restrict__ out) {
  __shared__ u16 P[16 * 232];      // 16 q-rows x 208 k-cols (+pad), conflict-free b128
  const int l = threadIdx.x;
  const int lg = l >> 4, li = l & 15;
  const int lin = blockIdx.x;
  const int work = (lin & 7) * (AWG / 8) + (lin >> 3);   // bijective XCD chunking
  const int bh = work / 13, qf = work - bh * 13;
  const int b = bh / NH, h = bh - b * NH;

  // zero tail cols 208..231 (read by PV t-loop, never written)
  for (int t = l; t < 16 * 24; t += 64) {
    int rr = t / 24, cc = t - rr * 24;
    P[rr * 232 + 208 + cc] = 0;
  }

  const u16* Qb = Qw + (size_t)bh * SP * DH;
  const u16* Kb = Kw + (size_t)bh * SP * DH;
  const u16* Vb = Vt + (size_t)bh * DH * VP;
  const u16* Bhp = Bxt + (size_t)h * 208 * 208 + qf * 16 + lg * 4;  // row k, cols j=0..3

  // ---- Q frags ----
  s16x8 a0 = *(const s16x8*)(Qb + (size_t)(qf * 16 + li) * DH + lg * 8);
  s16x8 a1 = *(const s16x8*)(Qb + (size_t)(qf * 16 + li) * DH + 32 + lg * 8);

  // ---- batched bias loads (13 x 8B, L2-hot 1MB table) ----
  u16x4 bb[13];
#pragma unroll
  for (int kf = 0; kf < 13; ++kf)
    bb[kf] = *(const u16x4*)(Bhp + (size_t)(kf * 16 + li) * 208);

  // ---- QK^T with 3-deep K-frag pipeline ----
  s16x8 kb0[3], kb1[3];
#pragma unroll
  for (int p = 0; p < 3; ++p) {
    kb0[p] = *(const s16x8*)(Kb + (size_t)(p * 16 + li) * DH + lg * 8);
    kb1[p] = *(const s16x8*)(Kb + (size_t)(p * 16 + li) * DH + 32 + lg * 8);
  }
  f32x4 S[13];
#pragma unroll
  for (int kf = 0; kf < 13; ++kf) {
    const int slot = kf % 3;                     // static (fully unrolled)
    f32x4 c = {};
    c = __builtin_amdgcn_mfma_f32_16x16x32_bf16(a0, kb0[slot], c, 0, 0, 0);
    c = __builtin_amdgcn_mfma_f32_16x16x32_bf16(a1, kb1[slot], c, 0, 0, 0);
    if (kf + 3 < 13) {
      kb0[slot] = *(const s16x8*)(Kb + (size_t)((kf + 3) * 16 + li) * DH + lg * 8);
      kb1[slot] = *(const s16x8*)(Kb + (size_t)((kf + 3) * 16 + li) * DH + 32 + lg * 8);
    }
#pragma unroll
    for (int j = 0; j < 4; ++j)
      S[kf][j] = c[j] + bf2f(bb[kf][j]);         // bias (+mask baked in)
  }

  // ---- softmax over 13 regs x 16 lanes (per 16-lane group) ----
  float rinv[4];
#pragma unroll
  for (int j = 0; j < 4; ++j) {
    float m = S[0][j];
#pragma unroll
    for (int kf = 1; kf < 13; ++kf) m = fmaxf(m, S[kf][j]);
    m = fmaxf(m, __shfl_xor(m, 1));
    m = fmaxf(m, __shfl_xor(m, 2));
    m = fmaxf(m, __shfl_xor(m, 4));
    m = fmaxf(m, __shfl_xor(m, 8));
    float sum = 0.f;
#pragma unroll
    for (int kf = 0; kf < 13; ++kf) {
      float p = __expf(S[kf][j] - m);
      S[kf][j] = p;
      sum += p;
    }
    sum += __shfl_xor(sum, 1);
    sum += __shfl_xor(sum, 2);
    sum += __shfl_xor(sum, 4);
    sum += __shfl_xor(sum, 8);
    rinv[j] = 1.0f / sum;
  }

  // ---- transpose P into LDS (bf16) ----
#pragma unroll
  for (int kf = 0; kf < 13; ++kf)
#pragma unroll
    for (int j = 0; j < 4; ++j)
      P[(lg * 4 + j) * 232 + kf * 16 + li] = f2bf(S[kf][j]);

  // ---- PV with 4-deep V-frag pipeline (flat u = nf*7+t) ----
  s16x8 vb[4];
#pragma unroll
  for (int p = 0; p < 4; ++p)
    vb[p] = *(const s16x8*)(Vb + (size_t)((p / 7) * 16 + li) * VP + (p % 7) * 32 + lg * 8);
  f32x4 o[4];
#pragma unroll
  for (int nf = 0; nf < 4; ++nf) {
    f32x4 c = {};
#pragma unroll
    for (int t = 0; t < 7; ++t) {
      const int u = nf * 7 + t, slot = u & 3;    // static (fully unrolled)
      s16x8 pa = *(const s16x8*)(&P[li * 232 + t * 32 + lg * 8]);
      c = __builtin_amdgcn_mfma_f32_16x16x32_bf16(pa, vb[slot], c, 0, 0, 0);
      if (u + 4 < 28) {
        const int u2 = u + 4;
        vb[slot] = *(const s16x8*)(Vb + (size_t)((u2 / 7) * 16 + li) * VP + (u2 % 7) * 32 + lg * 8);
      }
    }
    o[nf] = c;
  }
#pragma unroll
  for (int nf = 0; nf < 4; ++nf) {
#pragma unroll
    for (int j = 0; j < 4; ++j) {
      int q = qf * 16 + lg * 4 + j;
      if (q < SEQ)
        out[((size_t)(b * SEQ + q)) * HID + h * DH + nf * 16 + li] = o[nf][j] * rinv[j];
    }
  }
}

extern "C" void kernel_launch(void* const* d_in, const int* in_sizes, int n_in,
                              void* d_out, int out_size, void* d_ws, size_t ws_size,
                              hipStream_t stream) {
  const float* hidden = (const float*)d_in[0];
  const float* Wq = (const float*)d_in[1];
  const float* bq = (const float*)d_in[2];
  const float* Wk = (const float*)d_in[3];
  const float* Wv = (const float*)d_in[4];
  const float* bv = (const float*)d_in[5];
  const float* btab = (const float*)d_in[6];
  float* out = (float*)d_out;

  // workspace layout (peak 85,260,288 B; Vt overlays dead Xb/Wt after qkv):
  char* ws = (char*)d_ws;
  u16* Xb  = (u16*)(ws);                       // [0, 19,365,888)   12608*768*2
  u16* Wt  = (u16*)(ws + 19365888);            // [.., 22,904,832)  2304*768*2
  float* bc = (float*)(ws + 22904832);         // [.., 22,914,048)  2304*4
  u16* Bxt = (u16*)(ws + 22914048);            // [.., 23,952,384)  12*208*208*2 bf16
  u16* Qw  = (u16*)(ws + 24990720);            // [.., 45,437,952)  768*208*64*2
  u16* Kw  = (u16*)(ws + 45437952);            // [.., 65,885,184)  768*208*64*2
  u16* Vw  = (u16*)(ws + 65885184);            // [.., 85,260,288)  768*197*64*2
  u16* Vt  = (u16*)(ws);                       // overlays Xb/Wt: 768*64*224*2 = 22,020,096

  conv_x<<<dim3(4728), dim3(256), 0, stream>>>(hidden, Xb, (MROWS * HID) / 8);
  conv_w<<<dim3(NCAT / 64, HID / 64), dim3(256), 0, stream>>>(Wq, Wk, Wv, Wt);
  conv_b<<<dim3(9), dim3(256), 0, stream>>>(bq, bv, bc);
  qkv_gemm<<<dim3(NWG), dim3(256), 0, stream>>>(Xb, Wt, bc, Qw, Kw, Vw);
  transpose_v<<<dim3(768), dim3(256), 0, stream>>>(Vw, Vt);
  expand_bias<<<dim3((NH * 208 * 208 + 255) / 256), dim3(256), 0, stream>>>(btab, Bxt);
  attn<<<dim3(AWG), dim3(64), 0, stream>>>(Qw, Kw, Vt, Bxt, out);
}

// Round 11
// 158.030 us; speedup vs baseline: 1.0520x; 1.0310x over previous
//
#include <hip/hip_runtime.h>
#include <hip/hip_bf16.h>
#include <stdint.h>

typedef unsigned short u16;
typedef __attribute__((ext_vector_type(4))) float f32x4;
typedef __attribute__((ext_vector_type(8))) short s16x8;
typedef __attribute__((ext_vector_type(4))) unsigned short u16x4;
typedef __attribute__((ext_vector_type(4))) float fvec4;

#define NH 12
#define DH 64
#define HID 768
#define SEQ 197
#define SP 208            // padded seq rows for Q/K slabs
#define VP 224            // padded seq cols for Vt slab
#define NREL 732
#define BATCH 64
#define MROWS (BATCH*SEQ) // 12608
#define NCAT (3*HID)      // 2304
#define AWG (768*13)      // 9984 attn blocks = 8 * 1248

// qkv 8-phase geometry: 256x256 tile, BK=64, 12 K-tiles
#define QBK 64
#define QMT 50            // 50*256 = 12800 >= 12608
#define QNT 9             // 9*256 = 2304
#define QWG (QMT*QNT)     // 450

static __device__ __forceinline__ u16 f2bf(float f) {
  union { float f; uint32_t u; } v; v.f = f;
  uint32_t u = v.u;
  return (u16)((u + 0x7FFFu + ((u >> 16) & 1u)) >> 16);
}
static __device__ __forceinline__ float bf2f(u16 v) {
  union { uint32_t u; float f; } x; x.u = ((uint32_t)v) << 16; return x.f;
}

// ---------------- prep: hidden fp32 -> bf16 ----------------
__global__ __launch_bounds__(256) void conv_x(const float* __restrict__ x, u16* __restrict__ xb, int n8) {
  int i = blockIdx.x * 256 + threadIdx.x;
  if (i >= n8) return;
  fvec4 a = ((const fvec4*)x)[2 * i];
  fvec4 b = ((const fvec4*)x)[2 * i + 1];
  s16x8 r;
  r[0] = (short)f2bf(a[0]); r[1] = (short)f2bf(a[1]); r[2] = (short)f2bf(a[2]); r[3] = (short)f2bf(a[3]);
  r[4] = (short)f2bf(b[0]); r[5] = (short)f2bf(b[1]); r[6] = (short)f2bf(b[2]); r[7] = (short)f2bf(b[3]);
  ((s16x8*)xb)[i] = r;
}

// ---------------- prep: W's -> transposed concat bf16 [NCAT][HID] ----------------
__global__ __launch_bounds__(256) void conv_w(const float* __restrict__ Wq, const float* __restrict__ Wk,
                                              const float* __restrict__ Wv, u16* __restrict__ Wt) {
  __shared__ float t[64][65];
  int n0 = blockIdx.x * 64;  // output row block (0..2303)
  int k0 = blockIdx.y * 64;  // k block (0..767)
  int m = n0 / HID;
  const float* W = (m == 0) ? Wq : ((m == 1) ? Wk : Wv);
  int nn0 = n0 - m * HID;
  for (int i = threadIdx.x; i < 64 * 64; i += 256) {
    int r = i >> 6, c = i & 63;
    t[r][c] = W[(size_t)(k0 + r) * HID + nn0 + c];   // coalesced read
  }
  __syncthreads();
  for (int i = threadIdx.x; i < 64 * 64; i += 256) {
    int r = i >> 6, c = i & 63;
    Wt[(size_t)(n0 + r) * HID + k0 + c] = f2bf(t[c][r]);  // coalesced write
  }
}

// ---------------- prep: bias concat (bq, 0, bv) ----------------
__global__ __launch_bounds__(256) void conv_b(const float* __restrict__ bq, const float* __restrict__ bv,
                                              float* __restrict__ bc) {
  int i = blockIdx.x * 256 + threadIdx.x;
  if (i < NCAT) {
    int m = i / HID, r = i - m * HID;
    bc[i] = (m == 0) ? bq[r] : ((m == 2) ? bv[r] : 0.f);
  }
}

// ---------------- prep: expand rel-pos bias, bf16, TRANSPOSED [NH][k=208][q=208] ----------------
__global__ __launch_bounds__(256) void expand_bias(const float* __restrict__ bias_table, u16* __restrict__ Bxt) {
  int i = blockIdx.x * 256 + threadIdx.x;
  if (i >= NH * 208 * 208) return;
  int h = i / (208 * 208);
  int r = i - h * 208 * 208;
  int k = r / 208, q = r - k * 208;
  float v;
  if (k >= SEQ) v = -1e30f;       // mask padded k
  else if (q >= SEQ) v = 0.f;     // padded q rows: unused
  else {
    int idx;
    if (q == 0) idx = (k == 0) ? 731 : 729;
    else if (k == 0) idx = 730;
    else {
      int iq = (q - 1) / 14, jq = (q - 1) % 14;
      int ik = (k - 1) / 14, jk = (k - 1) % 14;
      idx = (iq - ik + 13) * 27 + (jq - jk + 13);
    }
    v = bias_table[(size_t)idx * NH + h];
  }
  Bxt[i] = f2bf(v);
}

// ================= fused QKV GEMM: 8-phase 256x256 template =================
// 8 waves (2M x 4N), per-wave C = 128x64 (acc[8][4]). LDS: A0/B0 (even K-tiles),
// A1/B1 (odd) = 4 x 32KB = 128KB, [256 rows][64 cols] bf16, 128B rows with the
// r7-proven XOR swizzle (slot ^ (row&7)); staged via inverse-swizzled source.
// Phase = { vmcnt(6); s_barrier; ds_read frags; issue 1 stage-unit (16KB);
//           setprio(1); 16 MFMA; setprio(0) }. Quadrants = (M-half, N-half);
// each phase's stage targets a region already fully read (verified disjoint).
// Stage ledger (steady iter i over tiles a=2i,b=2i+1):
//   p0:A(b)pt2  p1:B(b)nh1  p2:A(a+2)pt1  p3:B(a+2)nh0
//   p4:A(a+2)pt2  p5:B(a+2)nh1  p6:A(b+2)pt1  p7:B(b+2)nh0
// vmcnt(6) forces the unit staged 4 phases earlier; reads need >=4-phase-old units.

#define VM6 asm volatile("s_waitcnt vmcnt(6)" ::: "memory")
#define VM4 asm volatile("s_waitcnt vmcnt(4)" ::: "memory")
#define VM0 asm volatile("s_waitcnt vmcnt(0)" ::: "memory")
#define SB  __builtin_amdgcn_sched_barrier(0)
#define BAR __builtin_amdgcn_s_barrier()
#define PH_SYNC6 { VM6; SB; BAR; SB; }

// stage one 16KB unit (16 x 1KB chunks); wave w covers chunks 2w, 2w+1 of the list.
// kind: 0 = part1 rows {0-63,128-191}; 1 = part2 rows {64-127,192-255};
//       2 = nh0 rows {wn*64+0..31};    3 = nh1 rows {wn*64+32..63}
static __device__ __forceinline__ void stage_u(const u16* __restrict__ gk, int grow0, int growmax,
                                               u16* lds, int w, int l, const int kind) {
#pragma unroll
  for (int i = 0; i < 2; ++i) {
    int t = 2 * w + i;
    int C;
    if (kind == 0)      C = (t < 8) ? t : (t + 8);
    else if (kind == 1) C = (t < 8) ? (t + 8) : (t + 16);
    else if (kind == 2) C = ((t >> 2) << 3) + (t & 3);
    else                C = ((t >> 2) << 3) + 4 + (t & 3);
    int r = C * 8 + (l >> 3);
    int grow = grow0 + r; if (grow > growmax) grow = growmax;
    int c = (l & 7) ^ (l >> 3);            // inverse swizzle on source
    const u16* g = gk + (size_t)grow * HID + c * 8;
    __builtin_amdgcn_global_load_lds((const __attribute__((address_space(1))) void*)g,
                                     (__attribute__((address_space(3))) void*)(lds + C * 512),
                                     16, 0, 0);
  }
}

static __device__ __forceinline__ s16x8 lds_frag(const u16* buf, int r, int s) {
  int c = s ^ (r & 7);
  return *(const s16x8*)((const char*)buf + r * 128 + c * 16);
}

__global__ __launch_bounds__(512, 1) void qkv_gemm(const u16* __restrict__ Xb, const u16* __restrict__ Wt,
                                                   const float* __restrict__ bc, u16* __restrict__ Qw,
                                                   u16* __restrict__ Kw, u16* __restrict__ Vw) {
  __shared__ u16 A0[256 * QBK], B0[256 * QBK];   // even K-tiles
  __shared__ u16 A1[256 * QBK], B1[256 * QBK];   // odd K-tiles
  const int tid = threadIdx.x;
  const int w = tid >> 6, l = tid & 63;
  const int wm = w >> 2, wn = w & 3;             // 2x4 wave grid
  const int lg = l >> 4, li = l & 15;

  // bijective XCD chunking: nwg=450, q=56, r=2
  const int lin = blockIdx.x;
  const int xcd = lin & 7;
  const int pos = lin >> 3;
  const int work = (xcd < 2 ? xcd * 57 : 114 + (xcd - 2) * 56) + pos;
  const int mt = work / QNT, nt = work - mt * QNT;
  const int arow0 = mt * 256, brow0 = nt * 256;
  const int AMAX = MROWS - 1, BMAX = NCAT - 1;

  f32x4 acc[8][4] = {};
  s16x8 af[4][2], bf0[2][2], bf1[2][2];

  // prologue: 6 units (tile0 full; tile1 pt1 + nh0)
  stage_u(Xb + 0 * QBK, arow0, AMAX, A0, w, l, 0);
  stage_u(Wt + 0 * QBK, brow0, BMAX, B0, w, l, 2);
  stage_u(Xb + 0 * QBK, arow0, AMAX, A0, w, l, 1);
  stage_u(Wt + 0 * QBK, brow0, BMAX, B0, w, l, 3);
  stage_u(Xb + 1 * QBK, arow0, AMAX, A1, w, l, 0);
  stage_u(Wt + 1 * QBK, brow0, BMAX, B1, w, l, 2);

#define LOAD_AF(BUF, MH)  _Pragma("unroll") for (int m2 = 0; m2 < 4; ++m2) _Pragma("unroll") \
    for (int kk = 0; kk < 2; ++kk) af[m2][kk] = lds_frag(BUF, wm * 128 + (MH) * 64 + m2 * 16 + li, kk * 4 + lg);
#define LOAD_BF(DST, BUF, NHh) _Pragma("unroll") for (int n2 = 0; n2 < 2; ++n2) _Pragma("unroll") \
    for (int kk = 0; kk < 2; ++kk) DST[n2][kk] = lds_frag(BUF, wn * 64 + (NHh) * 32 + n2 * 16 + li, kk * 4 + lg);
#define MFMA16(BFA, MH, NHh) { __builtin_amdgcn_s_setprio(1); _Pragma("unroll") \
    for (int m2 = 0; m2 < 4; ++m2) _Pragma("unroll") for (int n2 = 0; n2 < 2; ++n2) _Pragma("unroll") \
    for (int kk = 0; kk < 2; ++kk) \
      acc[(MH) * 4 + m2][(NHh) * 2 + n2] = __builtin_amdgcn_mfma_f32_16x16x32_bf16(af[m2][kk], BFA[n2][kk], acc[(MH) * 4 + m2][(NHh) * 2 + n2], 0, 0, 0); \
    __builtin_amdgcn_s_setprio(0); }

  for (int i = 0; i < 5; ++i) {                  // steady iterations (tiles 0..9)
    const int a = 2 * i, b = 2 * i + 1;
    const u16* Xa2 = Xb + (size_t)(a + 2) * QBK;
    const u16* Wa2 = Wt + (size_t)(a + 2) * QBK;
    const u16* Xb2 = Xb + (size_t)(b + 2) * QBK;
    const u16* Wb2 = Wt + (size_t)(b + 2) * QBK;
    // p0: tile a, mh0, nh0
    PH_SYNC6; LOAD_AF(A0, 0); LOAD_BF(bf0, B0, 0);
    stage_u(Xb + (size_t)b * QBK, arow0, AMAX, A1, w, l, 1);
    MFMA16(bf0, 0, 0);
    // p1: a, mh0, nh1
    PH_SYNC6; LOAD_BF(bf1, B0, 1);
    stage_u(Wt + (size_t)b * QBK, brow0, BMAX, B1, w, l, 3);
    MFMA16(bf1, 0, 1);
    // p2: a, mh1, nh0
    PH_SYNC6; LOAD_AF(A0, 1);
    stage_u(Xa2, arow0, AMAX, A0, w, l, 0);
    MFMA16(bf0, 1, 0);
    // p3: a, mh1, nh1
    PH_SYNC6;
    stage_u(Wa2, brow0, BMAX, B0, w, l, 2);
    MFMA16(bf1, 1, 1);
    // p4: tile b, mh0, nh0
    PH_SYNC6; LOAD_AF(A1, 0); LOAD_BF(bf0, B1, 0);
    stage_u(Xa2, arow0, AMAX, A0, w, l, 1);
    MFMA16(bf0, 0, 0);
    // p5: b, mh0, nh1
    PH_SYNC6; LOAD_BF(bf1, B1, 1);
    stage_u(Wa2, brow0, BMAX, B0, w, l, 3);
    MFMA16(bf1, 0, 1);
    // p6: b, mh1, nh0
    PH_SYNC6; LOAD_AF(A1, 1);
    stage_u(Xb2, arow0, AMAX, A1, w, l, 0);
    MFMA16(bf0, 1, 0);
    // p7: b, mh1, nh1
    PH_SYNC6;
    stage_u(Wb2, brow0, BMAX, B1, w, l, 2);
    MFMA16(bf1, 1, 1);
  }
  { // peeled last iteration: tiles 10 (A0/B0), 11 (A1/B1); no stages past tile 11
    PH_SYNC6; LOAD_AF(A0, 0); LOAD_BF(bf0, B0, 0);
    stage_u(Xb + 11 * QBK, arow0, AMAX, A1, w, l, 1);
    MFMA16(bf0, 0, 0);
    PH_SYNC6; LOAD_BF(bf1, B0, 1);
    stage_u(Wt + 11 * QBK, brow0, BMAX, B1, w, l, 3);
    MFMA16(bf1, 0, 1);
    PH_SYNC6; LOAD_AF(A0, 1); MFMA16(bf0, 1, 0);
    PH_SYNC6;                 MFMA16(bf1, 1, 1);
    { VM4; SB; BAR; SB; } LOAD_AF(A1, 0); LOAD_BF(bf0, B1, 0); MFMA16(bf0, 0, 0);
    { VM0; SB; BAR; SB; } LOAD_BF(bf1, B1, 1); MFMA16(bf1, 0, 1);
    { SB; BAR; SB; } LOAD_AF(A1, 1); MFMA16(bf0, 1, 0);
    { SB; BAR; SB; } MFMA16(bf1, 1, 1);
  }

  // ---------------- uniform m-pure epilogue (block-uniform dst/scale/stride) ----------------
  const int mblk = nt / 3;                 // 0=Q, 1=K, 2=V (256-col tiles never straddle)
  u16* __restrict__ dst = (mblk == 0) ? Qw : ((mblk == 1) ? Kw : Vw);
  const float scale = (mblk == 0) ? 0.125f : 1.0f;
  const int STR = (mblk == 2) ? SEQ : SP;
  int hv[4], dv[4]; float bcv[4];
#pragma unroll
  for (int ni = 0; ni < 4; ++ni) {
    int col = brow0 + wn * 64 + ni * 16 + li;
    int cloc = col - mblk * HID;
    hv[ni] = cloc >> 6; dv[ni] = cloc & 63;
    bcv[ni] = bc[col];
  }
#pragma unroll
  for (int mi = 0; mi < 8; ++mi) {
#pragma unroll
    for (int j = 0; j < 4; ++j) {
      int row = arow0 + wm * 128 + mi * 16 + lg * 4 + j;
      if (row < MROWS) {
        int b = row / SEQ, s = row - b * SEQ;
#pragma unroll
        for (int ni = 0; ni < 4; ++ni)
          dst[((size_t)(b * NH + hv[ni]) * STR + s) * DH + dv[ni]] = f2bf((acc[mi][ni][j] + bcv[ni]) * scale);
      }
    }
  }
}

// ---------------- transpose V: [bh][197][64] -> [bh][64][224] (tail zero) ----------------
__global__ __launch_bounds__(256) void transpose_v(const u16* __restrict__ Vw, u16* __restrict__ Vt) {
  __shared__ u16 T[64][209];
  const int bh = blockIdx.x;
  const int tid = threadIdx.x;
  const u16* src = Vw + (size_t)bh * SEQ * DH;
  for (int i = tid; i < 208 * 64; i += 256) {
    int r = i >> 6, c = i & 63;
    u16 v = (r < SEQ) ? src[(size_t)r * DH + c] : (u16)0;
    T[c][r] = v;
  }
  __syncthreads();
  uint32_t* __restrict__ dst = (uint32_t*)(Vt + (size_t)bh * DH * VP);
  for (int i = tid; i < 64 * 112; i += 256) {
    int d = i / 112, s2 = i - d * 112;
    uint32_t v = 0;
    if (s2 < 104) v = (uint32_t)T[d][2 * s2] | ((uint32_t)T[d][2 * s2 + 1] << 16);
    dst[(size_t)d * 112 + s2] = v;
  }
}

// ---------------- fused attention: 1 WAVE per (bh, qf), ILP-pipelined ----------------
__global__ __launch_bounds__(64, 3) void attn(const u16* __restrict__ Qw, const u16* __restrict__ Kw,
                                              const u16* __restrict__ Vt, const u16* __restrict__ Bxt,
                                              float* __restrict__ out) {
  __shared__ u16 P[16 * 232];
  const int l = threadIdx.x;
  const int lg = l >> 4, li = l & 15;
  const int lin = blockIdx.x;
  const int work = (lin & 7) * (AWG / 8) + (lin >> 3);   // bijective XCD chunking
  const int bh = work / 13, qf = work - bh * 13;
  const int b = bh / NH, h = bh - b * NH;

  for (int t = l; t < 16 * 24; t += 64) {
    int rr = t / 24, cc = t - rr * 24;
    P[rr * 232 + 208 + cc] = 0;
  }

  const u16* Qb = Qw + (size_t)bh * SP * DH;
  const u16* Kb = Kw + (size_t)bh * SP * DH;
  const u16* Vb = Vt + (size_t)bh * DH * VP;
  const u16* Bhp = Bxt + (size_t)h * 208 * 208 + qf * 16 + lg * 4;

  s16x8 a0 = *(const s16x8*)(Qb + (size_t)(qf * 16 + li) * DH + lg * 8);
  s16x8 a1 = *(const s16x8*)(Qb + (size_t)(qf * 16 + li) * DH + 32 + lg * 8);

  u16x4 bb[13];
#pragma unroll
  for (int kf = 0; kf < 13; ++kf)
    bb[kf] = *(const u16x4*)(Bhp + (size_t)(kf * 16 + li) * 208);

  s16x8 kb0[3], kb1[3];
#pragma unroll
  for (int p = 0; p < 3; ++p) {
    kb0[p] = *(const s16x8*)(Kb + (size_t)(p * 16 + li) * DH + lg * 8);
    kb1[p] = *(const s16x8*)(Kb + (size_t)(p * 16 + li) * DH + 32 + lg * 8);
  }
  f32x4 S[13];
#pragma unroll
  for (int kf = 0; kf < 13; ++kf) {
    const int slot = kf % 3;
    f32x4 c = {};
    c = __builtin_amdgcn_mfma_f32_16x16x32_bf16(a0, kb0[slot], c, 0, 0, 0);
    c = __builtin_amdgcn_mfma_f32_16x16x32_bf16(a1, kb1[slot], c, 0, 0, 0);
    if (kf + 3 < 13) {
      kb0[slot] = *(const s16x8*)(Kb + (size_t)((kf + 3) * 16 + li) * DH + lg * 8);
      kb1[slot] = *(const s16x8*)(Kb + (size_t)((kf + 3) * 16 + li) * DH + 32 + lg * 8);
    }
#pragma unroll
    for (int j = 0; j < 4; ++j)
      S[kf][j] = c[j] + bf2f(bb[kf][j]);
  }

  float rinv[4];
#pragma unroll
  for (int j = 0; j < 4; ++j) {
    float m = S[0][j];
#pragma unroll
    for (int kf = 1; kf < 13; ++kf) m = fmaxf(m, S[kf][j]);
    m = fmaxf(m, __shfl_xor(m, 1));
    m = fmaxf(m, __shfl_xor(m, 2));
    m = fmaxf(m, __shfl_xor(m, 4));
    m = fmaxf(m, __shfl_xor(m, 8));
    float sum = 0.f;
#pragma unroll
    for (int kf = 0; kf < 13; ++kf) {
      float p = __expf(S[kf][j] - m);
      S[kf][j] = p;
      sum += p;
    }
    sum += __shfl_xor(sum, 1);
    sum += __shfl_xor(sum, 2);
    sum += __shfl_xor(sum, 4);
    sum += __shfl_xor(sum, 8);
    rinv[j] = 1.0f / sum;
  }

#pragma unroll
  for (int kf = 0; kf < 13; ++kf)
#pragma unroll
    for (int j = 0; j < 4; ++j)
      P[(lg * 4 + j) * 232 + kf * 16 + li] = f2bf(S[kf][j]);

  s16x8 vb[4];
#pragma unroll
  for (int p = 0; p < 4; ++p)
    vb[p] = *(const s16x8*)(Vb + (size_t)((p / 7) * 16 + li) * VP + (p % 7) * 32 + lg * 8);
  f32x4 o[4];
#pragma unroll
  for (int nf = 0; nf < 4; ++nf) {
    f32x4 c = {};
#pragma unroll
    for (int t = 0; t < 7; ++t) {
      const int u = nf * 7 + t, slot = u & 3;
      s16x8 pa = *(const s16x8*)(&P[li * 232 + t * 32 + lg * 8]);
      c = __builtin_amdgcn_mfma_f32_16x16x32_bf16(pa, vb[slot], c, 0, 0, 0);
      if (u + 4 < 28) {
        const int u2 = u + 4;
        vb[slot] = *(const s16x8*)(Vb + (size_t)((u2 / 7) * 16 + li) * VP + (u2 % 7) * 32 + lg * 8);
      }
    }
    o[nf] = c;
  }
#pragma unroll
  for (int nf = 0; nf < 4; ++nf) {
#pragma unroll
    for (int j = 0; j < 4; ++j) {
      int q = qf * 16 + lg * 4 + j;
      if (q < SEQ)
        out[((size_t)(b * SEQ + q)) * HID + h * DH + nf * 16 + li] = o[nf][j] * rinv[j];
    }
  }
}

extern "C" void kernel_launch(void* const* d_in, const int* in_sizes, int n_in,
                              void* d_out, int out_size, void* d_ws, size_t ws_size,
                              hipStream_t stream) {
  const float* hidden = (const float*)d_in[0];
  const float* Wq = (const float*)d_in[1];
  const float* bq = (const float*)d_in[2];
  const float* Wk = (const float*)d_in[3];
  const float* Wv = (const float*)d_in[4];
  const float* bv = (const float*)d_in[5];
  const float* btab = (const float*)d_in[6];
  float* out = (float*)d_out;

  // workspace layout (peak 85,260,288 B; Vt overlays dead Xb/Wt after qkv):
  char* ws = (char*)d_ws;
  u16* Xb  = (u16*)(ws);                       // [0, 19,365,888)   12608*768*2
  u16* Wt  = (u16*)(ws + 19365888);            // [.., 22,904,832)  2304*768*2
  float* bc = (float*)(ws + 22904832);         // [.., 22,914,048)  2304*4
  u16* Bxt = (u16*)(ws + 22914048);            // [.., 23,952,384)  12*208*208*2 bf16
  u16* Qw  = (u16*)(ws + 24990720);            // [.., 45,437,952)  768*208*64*2
  u16* Kw  = (u16*)(ws + 45437952);            // [.., 65,885,184)  768*208*64*2
  u16* Vw  = (u16*)(ws + 65885184);            // [.., 85,260,288)  768*197*64*2
  u16* Vt  = (u16*)(ws);                       // overlays Xb/Wt: 768*64*224*2 = 22,020,096

  conv_x<<<dim3(4728), dim3(256), 0, stream>>>(hidden, Xb, (MROWS * HID) / 8);
  conv_w<<<dim3(NCAT / 64, HID / 64), dim3(256), 0, stream>>>(Wq, Wk, Wv, Wt);
  conv_b<<<dim3(9), dim3(256), 0, stream>>>(bq, bv, bc);
  qkv_gemm<<<dim3(QWG), dim3(512), 0, stream>>>(Xb, Wt, bc, Qw, Kw, Vw);
  transpose_v<<<dim3(768), dim3(256), 0, stream>>>(Vw, Vt);
  expand_bias<<<dim3((NH * 208 * 208 + 255) / 256), dim3(256), 0, stream>>>(btab, Bxt);
  attn<<<dim3(AWG), dim3(64), 0, stream>>>(Qw, Kw, Vt, Bxt, out);
}

// Round 12
// 141.124 us; speedup vs baseline: 1.1780x; 1.1198x over previous
//
#include <hip/hip_runtime.h>
#include <hip/hip_bf16.h>
#include <stdint.h>

typedef unsigned short u16;
typedef __attribute__((ext_vector_type(4))) float f32x4;
typedef __attribute__((ext_vector_type(8))) short s16x8;
typedef __attribute__((ext_vector_type(4))) unsigned short u16x4;
typedef __attribute__((ext_vector_type(4))) float fvec4;

#define NH 12
#define DH 64
#define HID 768
#define SEQ 197
#define VP 224            // padded seq cols for Vt slab
#define NREL 732
#define BATCH 64
#define MROWS (BATCH*SEQ) // 12608
#define NCAT (3*HID)      // 2304
#define BK 64
#define MT 99             // grid tiles in M (99*128 = 12672 >= 12608)
#define NT 18             // grid tiles in N (18*128 = 2304)
#define NWG (MT*NT)       // 1782
#define AWG (768*13)      // 9984 attn blocks = 8 * 1248
#define QKSTRIDE (SEQ*DH) // 12608 u16 per bh slab (tight)

static __device__ __forceinline__ u16 f2bf(float f) {
  union { float f; uint32_t u; } v; v.f = f;
  uint32_t u = v.u;
  return (u16)((u + 0x7FFFu + ((u >> 16) & 1u)) >> 16);
}
static __device__ __forceinline__ float bf2f(u16 v) {
  union { uint32_t u; float f; } x; x.u = ((uint32_t)v) << 16; return x.f;
}

// ---------------- prep: hidden fp32 -> bf16 ----------------
__global__ __launch_bounds__(256) void conv_x(const float* __restrict__ x, u16* __restrict__ xb, int n8) {
  int i = blockIdx.x * 256 + threadIdx.x;
  if (i >= n8) return;
  fvec4 a = ((const fvec4*)x)[2 * i];
  fvec4 b = ((const fvec4*)x)[2 * i + 1];
  s16x8 r;
  r[0] = (short)f2bf(a[0]); r[1] = (short)f2bf(a[1]); r[2] = (short)f2bf(a[2]); r[3] = (short)f2bf(a[3]);
  r[4] = (short)f2bf(b[0]); r[5] = (short)f2bf(b[1]); r[6] = (short)f2bf(b[2]); r[7] = (short)f2bf(b[3]);
  ((s16x8*)xb)[i] = r;
}

// ---------------- prep: W's -> transposed concat bf16 [NCAT][HID] ----------------
__global__ __launch_bounds__(256) void conv_w(const float* __restrict__ Wq, const float* __restrict__ Wk,
                                              const float* __restrict__ Wv, u16* __restrict__ Wt) {
  __shared__ float t[64][65];
  int n0 = blockIdx.x * 64;  // output row block (0..2303)
  int k0 = blockIdx.y * 64;  // k block (0..767)
  int m = n0 / HID;
  const float* W = (m == 0) ? Wq : ((m == 1) ? Wk : Wv);
  int nn0 = n0 - m * HID;
  for (int i = threadIdx.x; i < 64 * 64; i += 256) {
    int r = i >> 6, c = i & 63;
    t[r][c] = W[(size_t)(k0 + r) * HID + nn0 + c];   // coalesced read
  }
  __syncthreads();
  for (int i = threadIdx.x; i < 64 * 64; i += 256) {
    int r = i >> 6, c = i & 63;
    Wt[(size_t)(n0 + r) * HID + k0 + c] = f2bf(t[c][r]);  // coalesced write
  }
}

// ---------------- prep: bias concat (bq, 0, bv) ----------------
__global__ __launch_bounds__(256) void conv_b(const float* __restrict__ bq, const float* __restrict__ bv,
                                              float* __restrict__ bc) {
  int i = blockIdx.x * 256 + threadIdx.x;
  if (i < NCAT) {
    int m = i / HID, r = i - m * HID;
    bc[i] = (m == 0) ? bq[r] : ((m == 2) ? bv[r] : 0.f);
  }
}

// ---------------- prep: expand rel-pos bias, bf16, TRANSPOSED [NH][k=208][q=208] ----------------
__global__ __launch_bounds__(256) void expand_bias(const float* __restrict__ bias_table, u16* __restrict__ Bxt) {
  int i = blockIdx.x * 256 + threadIdx.x;
  if (i >= NH * 208 * 208) return;
  int h = i / (208 * 208);
  int r = i - h * 208 * 208;
  int k = r / 208, q = r - k * 208;
  float v;
  if (k >= SEQ) v = -1e30f;       // mask padded k (incl. cross-slab garbage reads)
  else if (q >= SEQ) v = 0.f;     // padded q rows: outputs discarded
  else {
    int idx;
    if (q == 0) idx = (k == 0) ? 731 : 729;
    else if (k == 0) idx = 730;
    else {
      int iq = (q - 1) / 14, jq = (q - 1) % 14;
      int ik = (k - 1) / 14, jk = (k - 1) % 14;
      idx = (iq - ik + 13) * 27 + (jq - jk + 13);
    }
    v = bias_table[(size_t)idx * NH + h];
  }
  Bxt[i] = f2bf(v);
}

// ---------------- fused QKV GEMM (r7-proven core + fused V-transpose epilogue) ----------------
// 128x128 tile, BK=64, 4 waves (2x2), double-buffered (64 KiB LDS union -> 2
// blocks/CU). Per K-step: stage(t+1 -> other buf), compute(t), ONE __syncthreads.
// XOR-swizzled LDS via inverse-swizzled source. Epilogue: Q/K direct (tight 197-
// row slabs); V transposed through the now-dead staging LDS and stored
// s-contiguous into Vt[bh][64][224] -- the separate transpose_v kernel is gone.

static __device__ __forceinline__ void stage128(const u16* __restrict__ gbase, int grow0, int growmax,
                                                u16* lds, int w, int l) {
#pragma unroll
  for (int i = 0; i < 4; ++i) {
    int ch = w * 4 + i;                    // wave-uniform 0..15
    int r = ch * 8 + (l >> 3);
    int grow = grow0 + r; if (grow > growmax) grow = growmax;
    int c = (l & 7) ^ (l >> 3);            // inverse swizzle on source
    const u16* g = gbase + (size_t)grow * HID + c * 8;
    __builtin_amdgcn_global_load_lds((const __attribute__((address_space(1))) void*)g,
                                     (__attribute__((address_space(3))) void*)(lds + ch * 512),
                                     16, 0, 0);
  }
}

static __device__ __forceinline__ void compute128(const u16* As, const u16* Bs, int wr, int wc,
                                                  int li, int lg, f32x4 acc[4][4]) {
#pragma unroll
  for (int kk = 0; kk < 2; ++kk) {
    s16x8 af[4], bf[4];
#pragma unroll
    for (int mi = 0; mi < 4; ++mi) {
      int r = wr * 64 + mi * 16 + li;
      int c = (kk * 4 + lg) ^ (r & 7);
      af[mi] = *(const s16x8*)((const char*)As + r * 128 + c * 16);
    }
#pragma unroll
    for (int ni = 0; ni < 4; ++ni) {
      int r = wc * 64 + ni * 16 + li;
      int c = (kk * 4 + lg) ^ (r & 7);
      bf[ni] = *(const s16x8*)((const char*)Bs + r * 128 + c * 16);
    }
#pragma unroll
    for (int mi = 0; mi < 4; ++mi)
#pragma unroll
      for (int ni = 0; ni < 4; ++ni)
        acc[mi][ni] = __builtin_amdgcn_mfma_f32_16x16x32_bf16(af[mi], bf[ni], acc[mi][ni], 0, 0, 0);
  }
}

__global__ __launch_bounds__(256, 2) void qkv_gemm(const u16* __restrict__ Xb, const u16* __restrict__ Wt,
                                                   const float* __restrict__ bc, u16* __restrict__ Qw,
                                                   u16* __restrict__ Kw, u16* __restrict__ Vt) {
  __shared__ u16 LDSU[32768];               // 64 KiB union: staging buffers / V-transpose
  u16* As0 = LDSU;
  u16* Bs0 = LDSU + 8192;
  u16* As1 = LDSU + 16384;
  u16* Bs1 = LDSU + 24576;
  const int tid = threadIdx.x;
  const int w = tid >> 6, l = tid & 63;
  const int wr = w >> 1, wc = w & 1;        // 2x2 wave grid, 64x64 per wave
  const int lg = l >> 4, li = l & 15;

  // bijective XCD chunking (m204): nwg=1782, q=222, r=6
  const int lin = blockIdx.x;
  const int xcd = lin & 7;
  const int pos = lin >> 3;
  const int work = (xcd < 6 ? xcd * 223 : 6 * 223 + (xcd - 6) * 222) + pos;
  const int mt = work / NT, nt = work - mt * NT;
  const int arow0 = mt * 128, brow0 = nt * 128;

  f32x4 acc[4][4] = {};

  stage128(Xb, arow0, MROWS - 1, As0, w, l);
  stage128(Wt, brow0, NCAT - 1, Bs0, w, l);
  __syncthreads();

  for (int kt2 = 0; kt2 < 6; ++kt2) {
    const int kt = kt2 * 2;
    stage128(Xb + (kt + 1) * BK, arow0, MROWS - 1, As1, w, l);
    stage128(Wt + (kt + 1) * BK, brow0, NCAT - 1, Bs1, w, l);
    compute128(As0, Bs0, wr, wc, li, lg, acc);
    __syncthreads();
    if (kt2 < 5) {
      stage128(Xb + (kt + 2) * BK, arow0, MROWS - 1, As0, w, l);
      stage128(Wt + (kt + 2) * BK, brow0, NCAT - 1, Bs0, w, l);
    }
    compute128(As1, Bs1, wr, wc, li, lg, acc);
    __syncthreads();                        // also frees LDSU for the V epilogue
  }

  const int mblk = nt / 6;                 // 0=Q, 1=K, 2=V (block-uniform)
  float bcv[4];
#pragma unroll
  for (int ni = 0; ni < 4; ++ni) bcv[ni] = bc[brow0 + wc * 64 + ni * 16 + li];

  if (mblk < 2) {
    // ---- Q/K: direct stores into tight [bh][197][64] slabs ----
    u16* __restrict__ dst = (mblk == 0) ? Qw : Kw;
    const float scale = (mblk == 0) ? 0.125f : 1.0f;
    int hv[4], dv[4];
#pragma unroll
    for (int ni = 0; ni < 4; ++ni) {
      int cloc = brow0 - mblk * HID + wc * 64 + ni * 16 + li;
      hv[ni] = cloc >> 6; dv[ni] = cloc & 63;
    }
#pragma unroll
    for (int mi = 0; mi < 4; ++mi) {
#pragma unroll
      for (int j = 0; j < 4; ++j) {
        int row = arow0 + wr * 64 + mi * 16 + lg * 4 + j;
        if (row < MROWS) {
          int b = row / SEQ, s = row - b * SEQ;
#pragma unroll
          for (int ni = 0; ni < 4; ++ni)
            dst[((size_t)(b * NH + hv[ni]) * SEQ + s) * DH + dv[ni]] = f2bf((acc[mi][ni][j] + bcv[ni]) * scale);
        }
      }
    }
  } else {
    // ---- V: transpose via reused LDS (stride-68 pad), store s-contiguous ----
    // wave w owns quadrant rows wr*64+[0,64), cols wc*64+[0,64); region w*4352.
#pragma unroll
    for (int mi = 0; mi < 4; ++mi) {
#pragma unroll
      for (int ni = 0; ni < 4; ++ni) {
        u16x4 pk;
#pragma unroll
        for (int j = 0; j < 4; ++j) pk[j] = f2bf(acc[mi][ni][j] + bcv[ni]);
        *(u16x4*)&LDSU[w * 4352 + (ni * 16 + li) * 68 + mi * 16 + lg * 4] = pk;
      }
    }
    __syncthreads();
    const int cw0 = brow0 - 2 * HID;       // V-local col base (2 heads per tile)
#pragma unroll 4
    for (int p = 0; p < 64; ++p) {
      int i = p * 256 + tid;
      int r = i & 127, c = i >> 7;         // lane-consecutive r -> coalesced store
      int wq = ((r >> 6) << 1) | (c >> 6);
      u16 v = LDSU[wq * 4352 + (c & 63) * 68 + (r & 63)];
      int row = arow0 + r;
      if (row < MROWS) {
        int b = row / SEQ, s = row - b * SEQ;
        int cl = cw0 + c;
        int h = cl >> 6, d = cl & 63;
        Vt[((size_t)(b * NH + h) * DH + d) * VP + s] = v;
      }
    }
  }
}

// ---------------- fused attention: 1 WAVE per (bh, qf), ILP-pipelined ----------------
__global__ __launch_bounds__(64, 3) void attn(const u16* __restrict__ Qw, const u16* __restrict__ Kw,
                                              const u16* __restrict__ Vt, const u16* __restrict__ Bxt,
                                              float* __restrict__ out) {
  __shared__ u16 P[16 * 232];
  const int l = threadIdx.x;
  const int lg = l >> 4, li = l & 15;
  const int lin = blockIdx.x;
  const int work = (lin & 7) * (AWG / 8) + (lin >> 3);   // bijective XCD chunking
  const int bh = work / 13, qf = work - bh * 13;
  const int b = bh / NH, h = bh - b * NH;

  for (int t = l; t < 16 * 24; t += 64) {
    int rr = t / 24, cc = t - rr * 24;
    P[rr * 232 + 208 + cc] = 0;
  }

  const u16* Qb = Qw + (size_t)bh * QKSTRIDE;
  const u16* Kb = Kw + (size_t)bh * QKSTRIDE;
  const u16* Vb = Vt + (size_t)bh * DH * VP;
  const u16* Bhp = Bxt + (size_t)h * 208 * 208 + qf * 16 + lg * 4;

  s16x8 a0 = *(const s16x8*)(Qb + (size_t)(qf * 16 + li) * DH + lg * 8);
  s16x8 a1 = *(const s16x8*)(Qb + (size_t)(qf * 16 + li) * DH + 32 + lg * 8);

  u16x4 bb[13];
#pragma unroll
  for (int kf = 0; kf < 13; ++kf)
    bb[kf] = *(const u16x4*)(Bhp + (size_t)(kf * 16 + li) * 208);

  s16x8 kb0[3], kb1[3];
#pragma unroll
  for (int p = 0; p < 3; ++p) {
    kb0[p] = *(const s16x8*)(Kb + (size_t)(p * 16 + li) * DH + lg * 8);
    kb1[p] = *(const s16x8*)(Kb + (size_t)(p * 16 + li) * DH + 32 + lg * 8);
  }
  f32x4 S[13];
#pragma unroll
  for (int kf = 0; kf < 13; ++kf) {
    const int slot = kf % 3;
    f32x4 c = {};
    c = __builtin_amdgcn_mfma_f32_16x16x32_bf16(a0, kb0[slot], c, 0, 0, 0);
    c = __builtin_amdgcn_mfma_f32_16x16x32_bf16(a1, kb1[slot], c, 0, 0, 0);
    if (kf + 3 < 13) {
      kb0[slot] = *(const s16x8*)(Kb + (size_t)((kf + 3) * 16 + li) * DH + lg * 8);
      kb1[slot] = *(const s16x8*)(Kb + (size_t)((kf + 3) * 16 + li) * DH + 32 + lg * 8);
    }
#pragma unroll
    for (int j = 0; j < 4; ++j)
      S[kf][j] = c[j] + bf2f(bb[kf][j]);
  }

  float rinv[4];
#pragma unroll
  for (int j = 0; j < 4; ++j) {
    float m = S[0][j];
#pragma unroll
    for (int kf = 1; kf < 13; ++kf) m = fmaxf(m, S[kf][j]);
    m = fmaxf(m, __shfl_xor(m, 1));
    m = fmaxf(m, __shfl_xor(m, 2));
    m = fmaxf(m, __shfl_xor(m, 4));
    m = fmaxf(m, __shfl_xor(m, 8));
    float sum = 0.f;
#pragma unroll
    for (int kf = 0; kf < 13; ++kf) {
      float p = __expf(S[kf][j] - m);
      S[kf][j] = p;
      sum += p;
    }
    sum += __shfl_xor(sum, 1);
    sum += __shfl_xor(sum, 2);
    sum += __shfl_xor(sum, 4);
    sum += __shfl_xor(sum, 8);
    rinv[j] = 1.0f / sum;
  }

#pragma unroll
  for (int kf = 0; kf < 13; ++kf)
#pragma unroll
    for (int j = 0; j < 4; ++j)
      P[(lg * 4 + j) * 232 + kf * 16 + li] = f2bf(S[kf][j]);

  s16x8 vb[4];
#pragma unroll
  for (int p = 0; p < 4; ++p)
    vb[p] = *(const s16x8*)(Vb + (size_t)((p / 7) * 16 + li) * VP + (p % 7) * 32 + lg * 8);
  f32x4 o[4];
#pragma unroll
  for (int nf = 0; nf < 4; ++nf) {
    f32x4 c = {};
#pragma unroll
    for (int t = 0; t < 7; ++t) {
      const int u = nf * 7 + t, slot = u & 3;
      s16x8 pa = *(const s16x8*)(&P[li * 232 + t * 32 + lg * 8]);
      c = __builtin_amdgcn_mfma_f32_16x16x32_bf16(pa, vb[slot], c, 0, 0, 0);
      if (u + 4 < 28) {
        const int u2 = u + 4;
        vb[slot] = *(const s16x8*)(Vb + (size_t)((u2 / 7) * 16 + li) * VP + (u2 % 7) * 32 + lg * 8);
      }
    }
    o[nf] = c;
  }
#pragma unroll
  for (int nf = 0; nf < 4; ++nf) {
#pragma unroll
    for (int j = 0; j < 4; ++j) {
      int q = qf * 16 + lg * 4 + j;
      if (q < SEQ)
        out[((size_t)(b * SEQ + q)) * HID + h * DH + nf * 16 + li] = o[nf][j] * rinv[j];
    }
  }
}

extern "C" void kernel_launch(void* const* d_in, const int* in_sizes, int n_in,
                              void* d_out, int out_size, void* d_ws, size_t ws_size,
                              hipStream_t stream) {
  const float* hidden = (const float*)d_in[0];
  const float* Wq = (const float*)d_in[1];
  const float* bq = (const float*)d_in[2];
  const float* Wk = (const float*)d_in[3];
  const float* Wv = (const float*)d_in[4];
  const float* bv = (const float*)d_in[5];
  const float* btab = (const float*)d_in[6];
  float* out = (float*)d_out;

  // workspace layout (peak 84,712,448 B, within previously-proven budget):
  char* ws = (char*)d_ws;
  u16* Xb  = (u16*)(ws);                       // [0, 19,365,888)   12608*768*2
  u16* Wt  = (u16*)(ws + 19365888);            // [.., 22,904,832)  2304*768*2
  float* bc = (float*)(ws + 22904832);         // [.., 22,914,048)  2304*4
  u16* Bxt = (u16*)(ws + 22914048);            // [.., 23,952,384)  12*208*208*2 bf16
  u16* Qw  = (u16*)(ws + 23952384);            // [.., 43,322,368)  (768*197+16)*64*2 tight
  u16* Kw  = (u16*)(ws + 43322368);            // [.., 62,692,352)  (768*197+16)*64*2 tight
  u16* Vt  = (u16*)(ws + 62692352);            // [.., 84,712,448)  768*64*224*2

  conv_x<<<dim3(4728), dim3(256), 0, stream>>>(hidden, Xb, (MROWS * HID) / 8);
  conv_w<<<dim3(NCAT / 64, HID / 64), dim3(256), 0, stream>>>(Wq, Wk, Wv, Wt);
  conv_b<<<dim3(9), dim3(256), 0, stream>>>(bq, bv, bc);
  qkv_gemm<<<dim3(NWG), dim3(256), 0, stream>>>(Xb, Wt, bc, Qw, Kw, Vt);
  expand_bias<<<dim3((NH * 208 * 208 + 255) / 256), dim3(256), 0, stream>>>(btab, Bxt);
  attn<<<dim3(AWG), dim3(64), 0, stream>>>(Qw, Kw, Vt, Bxt, out);
}

// Round 13
// 133.771 us; speedup vs baseline: 1.2428x; 1.0550x over previous
//
#include <hip/hip_runtime.h>
#include <hip/hip_bf16.h>
#include <stdint.h>

typedef unsigned short u16;
typedef __attribute__((ext_vector_type(4))) float f32x4;
typedef __attribute__((ext_vector_type(8))) short s16x8;
typedef __attribute__((ext_vector_type(4))) unsigned short u16x4;
typedef __attribute__((ext_vector_type(4))) float fvec4;

#define NH 12
#define DH 64
#define HID 768
#define SEQ 197
#define VP 224            // padded seq cols for Vt slab
#define NREL 732
#define BATCH 64
#define MROWS (BATCH*SEQ) // 12608
#define NCAT (3*HID)      // 2304
#define BK 64
#define MT 99             // grid tiles in M (99*128 = 12672 >= 12608)
#define NT 18             // grid tiles in N (18*128 = 2304)
#define NWG (MT*NT)       // 1782
#define AWG2 (768*7)      // 5376 attn blocks (2 q-frags each) = 8 * 672
#define QKSTRIDE (SEQ*DH) // 12608 u16 per bh slab (tight)

// prep_all block ranges
#define PB_X 4728                 // conv_x: 4728*256*8 = 12608*768
#define PB_W (PB_X + 432)         // conv_w: 36*12 tiles
#define PB_B (PB_W + 9)           // conv_b
#define PB_E (PB_B + 2028)        // expand_bias: 2028*256 = 519168 exact

static __device__ __forceinline__ u16 f2bf(float f) {
  union { float f; uint32_t u; } v; v.f = f;
  uint32_t u = v.u;
  return (u16)((u + 0x7FFFu + ((u >> 16) & 1u)) >> 16);
}
static __device__ __forceinline__ float bf2f(u16 v) {
  union { uint32_t u; float f; } x; x.u = ((uint32_t)v) << 16; return x.f;
}

// ---------------- fused prep: conv_x | conv_w | conv_b | expand_bias ----------------
__global__ __launch_bounds__(256) void prep_all(const float* __restrict__ x,
                                                const float* __restrict__ Wq, const float* __restrict__ Wk,
                                                const float* __restrict__ Wv, const float* __restrict__ bq,
                                                const float* __restrict__ bv, const float* __restrict__ btab,
                                                u16* __restrict__ xb, u16* __restrict__ Wt,
                                                float* __restrict__ bc, u16* __restrict__ Bxt) {
  __shared__ float t[64][65];
  const int bi = blockIdx.x;
  const int tid = threadIdx.x;
  if (bi < PB_X) {
    // hidden fp32 -> bf16, 8 elems/thread
    int i = bi * 256 + tid;
    fvec4 a = ((const fvec4*)x)[2 * i];
    fvec4 b = ((const fvec4*)x)[2 * i + 1];
    s16x8 r;
    r[0] = (short)f2bf(a[0]); r[1] = (short)f2bf(a[1]); r[2] = (short)f2bf(a[2]); r[3] = (short)f2bf(a[3]);
    r[4] = (short)f2bf(b[0]); r[5] = (short)f2bf(b[1]); r[6] = (short)f2bf(b[2]); r[7] = (short)f2bf(b[3]);
    ((s16x8*)xb)[i] = r;
  } else if (bi < PB_W) {
    // W's -> transposed concat bf16 [NCAT][HID]
    int f = bi - PB_X;
    int n0 = (f % 36) * 64, k0 = (f / 36) * 64;
    int m = n0 / HID;
    const float* W = (m == 0) ? Wq : ((m == 1) ? Wk : Wv);
    int nn0 = n0 - m * HID;
    for (int i = tid; i < 64 * 64; i += 256) {
      int r = i >> 6, c = i & 63;
      t[r][c] = W[(size_t)(k0 + r) * HID + nn0 + c];
    }
    __syncthreads();
    for (int i = tid; i < 64 * 64; i += 256) {
      int r = i >> 6, c = i & 63;
      Wt[(size_t)(n0 + r) * HID + k0 + c] = f2bf(t[c][r]);
    }
  } else if (bi < PB_B) {
    int i = (bi - PB_W) * 256 + tid;
    if (i < NCAT) {
      int m = i / HID, r = i - m * HID;
      bc[i] = (m == 0) ? bq[r] : ((m == 2) ? bv[r] : 0.f);
    }
  } else {
    // expand rel-pos bias, bf16, TRANSPOSED [NH][k=208][q=208]
    int i = (bi - PB_B) * 256 + tid;   // < 519168 exact
    int h = i / (208 * 208);
    int r = i - h * 208 * 208;
    int k = r / 208, q = r - k * 208;
    float v;
    if (k >= SEQ) v = -1e30f;          // mask padded k (incl. cross-slab garbage)
    else if (q >= SEQ) v = 0.f;        // padded q rows: outputs discarded
    else {
      int idx;
      if (q == 0) idx = (k == 0) ? 731 : 729;
      else if (k == 0) idx = 730;
      else {
        int iq = (q - 1) / 14, jq = (q - 1) % 14;
        int ik = (k - 1) / 14, jk = (k - 1) % 14;
        idx = (iq - ik + 13) * 27 + (jq - jk + 13);
      }
      v = btab[(size_t)idx * NH + h];
    }
    Bxt[i] = f2bf(v);
  }
}

// ---------------- fused QKV GEMM (r12-proven: ~73 us, fused V-transpose epilogue) ----------------
static __device__ __forceinline__ void stage128(const u16* __restrict__ gbase, int grow0, int growmax,
                                                u16* lds, int w, int l) {
#pragma unroll
  for (int i = 0; i < 4; ++i) {
    int ch = w * 4 + i;                    // wave-uniform 0..15
    int r = ch * 8 + (l >> 3);
    int grow = grow0 + r; if (grow > growmax) grow = growmax;
    int c = (l & 7) ^ (l >> 3);            // inverse swizzle on source
    const u16* g = gbase + (size_t)grow * HID + c * 8;
    __builtin_amdgcn_global_load_lds((const __attribute__((address_space(1))) void*)g,
                                     (__attribute__((address_space(3))) void*)(lds + ch * 512),
                                     16, 0, 0);
  }
}

static __device__ __forceinline__ void compute128(const u16* As, const u16* Bs, int wr, int wc,
                                                  int li, int lg, f32x4 acc[4][4]) {
#pragma unroll
  for (int kk = 0; kk < 2; ++kk) {
    s16x8 af[4], bf[4];
#pragma unroll
    for (int mi = 0; mi < 4; ++mi) {
      int r = wr * 64 + mi * 16 + li;
      int c = (kk * 4 + lg) ^ (r & 7);
      af[mi] = *(const s16x8*)((const char*)As + r * 128 + c * 16);
    }
#pragma unroll
    for (int ni = 0; ni < 4; ++ni) {
      int r = wc * 64 + ni * 16 + li;
      int c = (kk * 4 + lg) ^ (r & 7);
      bf[ni] = *(const s16x8*)((const char*)Bs + r * 128 + c * 16);
    }
#pragma unroll
    for (int mi = 0; mi < 4; ++mi)
#pragma unroll
      for (int ni = 0; ni < 4; ++ni)
        acc[mi][ni] = __builtin_amdgcn_mfma_f32_16x16x32_bf16(af[mi], bf[ni], acc[mi][ni], 0, 0, 0);
  }
}

__global__ __launch_bounds__(256, 2) void qkv_gemm(const u16* __restrict__ Xb, const u16* __restrict__ Wt,
                                                   const float* __restrict__ bc, u16* __restrict__ Qw,
                                                   u16* __restrict__ Kw, u16* __restrict__ Vt) {
  __shared__ u16 LDSU[32768];               // 64 KiB union: staging buffers / V-transpose
  u16* As0 = LDSU;
  u16* Bs0 = LDSU + 8192;
  u16* As1 = LDSU + 16384;
  u16* Bs1 = LDSU + 24576;
  const int tid = threadIdx.x;
  const int w = tid >> 6, l = tid & 63;
  const int wr = w >> 1, wc = w & 1;        // 2x2 wave grid, 64x64 per wave
  const int lg = l >> 4, li = l & 15;

  // bijective XCD chunking (m204): nwg=1782, q=222, r=6
  const int lin = blockIdx.x;
  const int xcd = lin & 7;
  const int pos = lin >> 3;
  const int work = (xcd < 6 ? xcd * 223 : 6 * 223 + (xcd - 6) * 222) + pos;
  const int mt = work / NT, nt = work - mt * NT;
  const int arow0 = mt * 128, brow0 = nt * 128;

  f32x4 acc[4][4] = {};

  stage128(Xb, arow0, MROWS - 1, As0, w, l);
  stage128(Wt, brow0, NCAT - 1, Bs0, w, l);
  __syncthreads();

  for (int kt2 = 0; kt2 < 6; ++kt2) {
    const int kt = kt2 * 2;
    stage128(Xb + (kt + 1) * BK, arow0, MROWS - 1, As1, w, l);
    stage128(Wt + (kt + 1) * BK, brow0, NCAT - 1, Bs1, w, l);
    compute128(As0, Bs0, wr, wc, li, lg, acc);
    __syncthreads();
    if (kt2 < 5) {
      stage128(Xb + (kt + 2) * BK, arow0, MROWS - 1, As0, w, l);
      stage128(Wt + (kt + 2) * BK, brow0, NCAT - 1, Bs0, w, l);
    }
    compute128(As1, Bs1, wr, wc, li, lg, acc);
    __syncthreads();                        // also frees LDSU for the V epilogue
  }

  const int mblk = nt / 6;                 // 0=Q, 1=K, 2=V (block-uniform)
  float bcv[4];
#pragma unroll
  for (int ni = 0; ni < 4; ++ni) bcv[ni] = bc[brow0 + wc * 64 + ni * 16 + li];

  if (mblk < 2) {
    u16* __restrict__ dst = (mblk == 0) ? Qw : Kw;
    const float scale = (mblk == 0) ? 0.125f : 1.0f;
    int hv[4], dv[4];
#pragma unroll
    for (int ni = 0; ni < 4; ++ni) {
      int cloc = brow0 - mblk * HID + wc * 64 + ni * 16 + li;
      hv[ni] = cloc >> 6; dv[ni] = cloc & 63;
    }
#pragma unroll
    for (int mi = 0; mi < 4; ++mi) {
#pragma unroll
      for (int j = 0; j < 4; ++j) {
        int row = arow0 + wr * 64 + mi * 16 + lg * 4 + j;
        if (row < MROWS) {
          int b = row / SEQ, s = row - b * SEQ;
#pragma unroll
          for (int ni = 0; ni < 4; ++ni)
            dst[((size_t)(b * NH + hv[ni]) * SEQ + s) * DH + dv[ni]] = f2bf((acc[mi][ni][j] + bcv[ni]) * scale);
        }
      }
    }
  } else {
    // V: transpose via reused LDS (stride-68 pad), store s-contiguous
#pragma unroll
    for (int mi = 0; mi < 4; ++mi) {
#pragma unroll
      for (int ni = 0; ni < 4; ++ni) {
        u16x4 pk;
#pragma unroll
        for (int j = 0; j < 4; ++j) pk[j] = f2bf(acc[mi][ni][j] + bcv[ni]);
        *(u16x4*)&LDSU[w * 4352 + (ni * 16 + li) * 68 + mi * 16 + lg * 4] = pk;
      }
    }
    __syncthreads();
    const int cw0 = brow0 - 2 * HID;       // V-local col base (2 heads per tile)
#pragma unroll 4
    for (int p = 0; p < 64; ++p) {
      int i = p * 256 + tid;
      int r = i & 127, c = i >> 7;         // lane-consecutive r -> coalesced store
      int wq = ((r >> 6) << 1) | (c >> 6);
      u16 v = LDSU[wq * 4352 + (c & 63) * 68 + (r & 63)];
      int row = arow0 + r;
      if (row < MROWS) {
        int b = row / SEQ, s = row - b * SEQ;
        int cl = cw0 + c;
        int h = cl >> 6, d = cl & 63;
        Vt[((size_t)(b * NH + h) * DH + d) * VP + s] = v;
      }
    }
  }
}

// ---------------- fused attention: 1 wave per (bh, q-PAIR) -- 2 q-frags share K/V ----------------
// r12 arithmetic: per-unit K+V slab re-reads = ~550 MB L2 traffic; 32 q-rows per
// wave halves it and doubles MFMA per load (108:84). VGPR ~220 -> (64,2).
__global__ __launch_bounds__(64, 2) void attn(const u16* __restrict__ Qw, const u16* __restrict__ Kw,
                                              const u16* __restrict__ Vt, const u16* __restrict__ Bxt,
                                              float* __restrict__ out) {
  __shared__ u16 P[2][16 * 232];
  const int l = threadIdx.x;
  const int lg = l >> 4, li = l & 15;
  const int lin = blockIdx.x;
  const int work = (lin & 7) * (AWG2 / 8) + (lin >> 3);   // bijective XCD chunking
  const int bh = work / 7, qp = work - bh * 7;
  const int b = bh / NH, h = bh - b * NH;
  const int q0 = qp * 32;

  // zero tail cols 208..231 of both P groups
  for (int t = l; t < 2 * 16 * 24; t += 64) {
    int g = t / (16 * 24), r2 = t - g * (16 * 24);
    int rr = r2 / 24, cc = r2 - rr * 24;
    P[g][rr * 232 + 208 + cc] = 0;
  }

  const u16* Qb = Qw + (size_t)bh * QKSTRIDE;
  const u16* Kb = Kw + (size_t)bh * QKSTRIDE;
  const u16* Vb = Vt + (size_t)bh * DH * VP;
  const u16* Bhp = Bxt + (size_t)h * 208 * 208 + q0 + lg * 4;

  // Q frags for both groups (rows q0+li, q0+16+li; garbage rows masked at store)
  s16x8 a0 = *(const s16x8*)(Qb + (size_t)(q0 + li) * DH + lg * 8);
  s16x8 a1 = *(const s16x8*)(Qb + (size_t)(q0 + li) * DH + 32 + lg * 8);
  s16x8 a2 = *(const s16x8*)(Qb + (size_t)(q0 + 16 + li) * DH + lg * 8);
  s16x8 a3 = *(const s16x8*)(Qb + (size_t)(q0 + 16 + li) * DH + 32 + lg * 8);

  // batched bias loads (row k = kf*16+li; group0 cols q0+lg*4, group1 +16)
  u16x4 bb0[13], bb1[13];
#pragma unroll
  for (int kf = 0; kf < 13; ++kf) {
    bb0[kf] = *(const u16x4*)(Bhp + (size_t)(kf * 16 + li) * 208);
    bb1[kf] = *(const u16x4*)(Bhp + (size_t)(kf * 16 + li) * 208 + 16);
  }

  // QK^T, 3-deep K pipeline, K frags feed BOTH groups
  s16x8 kb0[3], kb1[3];
#pragma unroll
  for (int p = 0; p < 3; ++p) {
    kb0[p] = *(const s16x8*)(Kb + (size_t)(p * 16 + li) * DH + lg * 8);
    kb1[p] = *(const s16x8*)(Kb + (size_t)(p * 16 + li) * DH + 32 + lg * 8);
  }
  f32x4 S0[13], S1[13];
#pragma unroll
  for (int kf = 0; kf < 13; ++kf) {
    const int slot = kf % 3;
    f32x4 c0 = {}, c1 = {};
    c0 = __builtin_amdgcn_mfma_f32_16x16x32_bf16(a0, kb0[slot], c0, 0, 0, 0);
    c0 = __builtin_amdgcn_mfma_f32_16x16x32_bf16(a1, kb1[slot], c0, 0, 0, 0);
    c1 = __builtin_amdgcn_mfma_f32_16x16x32_bf16(a2, kb0[slot], c1, 0, 0, 0);
    c1 = __builtin_amdgcn_mfma_f32_16x16x32_bf16(a3, kb1[slot], c1, 0, 0, 0);
    if (kf + 3 < 13) {
      kb0[slot] = *(const s16x8*)(Kb + (size_t)((kf + 3) * 16 + li) * DH + lg * 8);
      kb1[slot] = *(const s16x8*)(Kb + (size_t)((kf + 3) * 16 + li) * DH + 32 + lg * 8);
    }
#pragma unroll
    for (int j = 0; j < 4; ++j) {
      S0[kf][j] = c0[j] + bf2f(bb0[kf][j]);
      S1[kf][j] = c1[j] + bf2f(bb1[kf][j]);
    }
  }

  // softmax per group (16-lane groups over k)
  float rinv0[4], rinv1[4];
#pragma unroll
  for (int j = 0; j < 4; ++j) {
    float m0 = S0[0][j], m1 = S1[0][j];
#pragma unroll
    for (int kf = 1; kf < 13; ++kf) { m0 = fmaxf(m0, S0[kf][j]); m1 = fmaxf(m1, S1[kf][j]); }
    m0 = fmaxf(m0, __shfl_xor(m0, 1)); m1 = fmaxf(m1, __shfl_xor(m1, 1));
    m0 = fmaxf(m0, __shfl_xor(m0, 2)); m1 = fmaxf(m1, __shfl_xor(m1, 2));
    m0 = fmaxf(m0, __shfl_xor(m0, 4)); m1 = fmaxf(m1, __shfl_xor(m1, 4));
    m0 = fmaxf(m0, __shfl_xor(m0, 8)); m1 = fmaxf(m1, __shfl_xor(m1, 8));
    float s0 = 0.f, s1 = 0.f;
#pragma unroll
    for (int kf = 0; kf < 13; ++kf) {
      float p0 = __expf(S0[kf][j] - m0); S0[kf][j] = p0; s0 += p0;
      float p1 = __expf(S1[kf][j] - m1); S1[kf][j] = p1; s1 += p1;
    }
    s0 += __shfl_xor(s0, 1); s1 += __shfl_xor(s1, 1);
    s0 += __shfl_xor(s0, 2); s1 += __shfl_xor(s1, 2);
    s0 += __shfl_xor(s0, 4); s1 += __shfl_xor(s1, 4);
    s0 += __shfl_xor(s0, 8); s1 += __shfl_xor(s1, 8);
    rinv0[j] = 1.0f / s0; rinv1[j] = 1.0f / s1;
  }

  // transpose P into LDS (bf16), both groups
#pragma unroll
  for (int kf = 0; kf < 13; ++kf)
#pragma unroll
    for (int j = 0; j < 4; ++j) {
      P[0][(lg * 4 + j) * 232 + kf * 16 + li] = f2bf(S0[kf][j]);
      P[1][(lg * 4 + j) * 232 + kf * 16 + li] = f2bf(S1[kf][j]);
    }

  // PV: shared V pipeline (4-deep), both groups per V frag
  s16x8 vb[4];
#pragma unroll
  for (int p = 0; p < 4; ++p)
    vb[p] = *(const s16x8*)(Vb + (size_t)((p / 7) * 16 + li) * VP + (p % 7) * 32 + lg * 8);
  f32x4 o0[4], o1[4];
#pragma unroll
  for (int nf = 0; nf < 4; ++nf) {
    f32x4 c0 = {}, c1 = {};
#pragma unroll
    for (int t = 0; t < 7; ++t) {
      const int u = nf * 7 + t, slot = u & 3;
      s16x8 pa0 = *(const s16x8*)(&P[0][li * 232 + t * 32 + lg * 8]);
      s16x8 pa1 = *(const s16x8*)(&P[1][li * 232 + t * 32 + lg * 8]);
      c0 = __builtin_amdgcn_mfma_f32_16x16x32_bf16(pa0, vb[slot], c0, 0, 0, 0);
      c1 = __builtin_amdgcn_mfma_f32_16x16x32_bf16(pa1, vb[slot], c1, 0, 0, 0);
      if (u + 4 < 28) {
        const int u2 = u + 4;
        vb[slot] = *(const s16x8*)(Vb + (size_t)((u2 / 7) * 16 + li) * VP + (u2 % 7) * 32 + lg * 8);
      }
    }
    o0[nf] = c0; o1[nf] = c1;
  }
#pragma unroll
  for (int nf = 0; nf < 4; ++nf) {
#pragma unroll
    for (int j = 0; j < 4; ++j) {
      int qa = q0 + lg * 4 + j;
      int qb2 = q0 + 16 + lg * 4 + j;
      if (qa < SEQ)
        out[((size_t)(b * SEQ + qa)) * HID + h * DH + nf * 16 + li] = o0[nf][j] * rinv0[j];
      if (qb2 < SEQ)
        out[((size_t)(b * SEQ + qb2)) * HID + h * DH + nf * 16 + li] = o1[nf][j] * rinv1[j];
    }
  }
}

extern "C" void kernel_launch(void* const* d_in, const int* in_sizes, int n_in,
                              void* d_out, int out_size, void* d_ws, size_t ws_size,
                              hipStream_t stream) {
  const float* hidden = (const float*)d_in[0];
  const float* Wq = (const float*)d_in[1];
  const float* bq = (const float*)d_in[2];
  const float* Wk = (const float*)d_in[3];
  const float* Wv = (const float*)d_in[4];
  const float* bv = (const float*)d_in[5];
  const float* btab = (const float*)d_in[6];
  float* out = (float*)d_out;

  // workspace layout (peak 84,716,672 B; Qw/Kw have 32-row pads for qp=6 over-reads):
  char* ws = (char*)d_ws;
  u16* Xb  = (u16*)(ws);                       // [0, 19,365,888)   12608*768*2
  u16* Wt  = (u16*)(ws + 19365888);            // [.., 22,904,832)  2304*768*2
  float* bc = (float*)(ws + 22904832);         // [.., 22,914,048)  2304*4
  u16* Bxt = (u16*)(ws + 22914048);            // [.., 23,952,384)  12*208*208*2 (+128B pad)
  u16* Qw  = (u16*)(ws + 23952512);            // [.., 43,322,496)  (768*197+32)*64*2
  u16* Kw  = (u16*)(ws + 43322496);            // [.., 62,692,480)  (768*197+32)*64*2
  u16* Vt  = (u16*)(ws + 62692480);            // [.., 84,712,576)  768*64*224*2

  prep_all<<<dim3(PB_E), dim3(256), 0, stream>>>(hidden, Wq, Wk, Wv, bq, bv, btab, Xb, Wt, bc, Bxt);
  qkv_gemm<<<dim3(NWG), dim3(256), 0, stream>>>(Xb, Wt, bc, Qw, Kw, Vt);
  attn<<<dim3(AWG2), dim3(64), 0, stream>>>(Qw, Kw, Vt, Bxt, out);
}